// Round 1
// baseline (13967.500 us; speedup 1.0000x reference)
//
#include <hip/hip_runtime.h>
#include <hip/hip_bf16.h>

#define N_E 100000
#define N_C 50000
#define H 256
#define D_E 768
#define D_C 1024
#define E_EE 800000
#define E_EC 400000
#define E_CE 400000

#define BM 128
#define BN 128
#define KT 16

// ---------------- edge-count kernel: cnt[dst] += 1 ----------------
__global__ __launch_bounds__(256) void count_k(const int* __restrict__ dst, int E,
                                               float* __restrict__ cnt) {
    int i = blockIdx.x * 256 + threadIdx.x;
    if (i < E) atomicAdd(&cnt[dst[i]], 1.0f);
}

// ---------------- scatter-add: agg[dst] += src[srcIdx] ----------------
// 4 edges per block; 64 lanes per edge; each lane moves one float4 (16B).
__global__ __launch_bounds__(256) void scatter_k(const float* __restrict__ src,
                                                 const int* __restrict__ sidx,
                                                 const int* __restrict__ didx, int E,
                                                 float* __restrict__ agg) {
    int e = blockIdx.x * 4 + (threadIdx.x >> 6);
    if (e >= E) return;
    int lane = threadIdx.x & 63;
    int s = sidx[e];
    int d = didx[e];
    const float4 v = *reinterpret_cast<const float4*>(src + (size_t)s * H + lane * 4);
    float* o = agg + (size_t)d * H + lane * 4;
    atomicAdd(o + 0, v.x);
    atomicAdd(o + 1, v.y);
    atomicAdd(o + 2, v.z);
    atomicAdd(o + 3, v.w);
}

// ---------------- mean finalize: agg /= max(cnt,1) (in place) ----------------
__global__ __launch_bounds__(256) void meandiv_k(float* __restrict__ agg,
                                                 const float* __restrict__ cnt) {
    int row = blockIdx.x;
    float c = fmaxf(cnt[row], 1.0f);
    size_t i = (size_t)row * H + threadIdx.x;
    agg[i] = agg[i] / c;
}

// ---------------- fused GEMM: out = sum_p A_p @ W_p  (+bias) (+relu+res) ----------------
// All GEMMs have N == H == 256. W_p is [K_p, 256] row-major. A_p is [M, K_p] row-major.
struct GemmArgs {
    const float* A[4];
    const float* W[4];
    int K[4];
    int nPairs;
    const float* bias1;  // nullable
    const float* bias2;  // nullable
    const float* res;    // residual input (mode 1)
    float* out;
    int M;
    int mode;  // 0 = plain, 1 = relu(acc+bias)+res, 2 = acc+bias (pre-norm)
};

__global__ __launch_bounds__(256) void gemm_k(GemmArgs g) {
    __shared__ float As[KT][BM];
    __shared__ float Bs[KT][BN];
    const int tid = threadIdx.x;
    const int tx = tid & 15;   // output col group
    const int ty = tid >> 4;   // output row group
    const int row0 = blockIdx.x * BM;
    const int col0 = blockIdx.y * BN;

    float acc[8][8] = {};

    for (int p = 0; p < g.nPairs; ++p) {
        const float* __restrict__ A = g.A[p];
        const float* __restrict__ W = g.W[p];
        const int K = g.K[p];
        for (int k0 = 0; k0 < K; k0 += KT) {
            // A tile: 128 rows x 16 k, transposed into As[k][m]
#pragma unroll
            for (int i = 0; i < 2; ++i) {
                int f = tid * 2 + i;  // 0..511
                int r = f >> 2;       // 0..127
                int kq = f & 3;       // 0..3 (float4 along K)
                int grow = row0 + r;
                float4 v = make_float4(0.f, 0.f, 0.f, 0.f);
                if (grow < g.M)
                    v = *reinterpret_cast<const float4*>(A + (size_t)grow * K + k0 + kq * 4);
                As[kq * 4 + 0][r] = v.x;
                As[kq * 4 + 1][r] = v.y;
                As[kq * 4 + 2][r] = v.z;
                As[kq * 4 + 3][r] = v.w;
            }
            // B tile: 16 k x 128 cols, row-major float4
#pragma unroll
            for (int i = 0; i < 2; ++i) {
                int f = tid * 2 + i;
                int kr = f >> 5;   // 0..15
                int cq = f & 31;   // 0..31 (float4 along N)
                *reinterpret_cast<float4*>(&Bs[kr][cq * 4]) =
                    *reinterpret_cast<const float4*>(W + (size_t)(k0 + kr) * H + col0 + cq * 4);
            }
            __syncthreads();
#pragma unroll
            for (int kt = 0; kt < KT; ++kt) {
                float ra[8], rb[8];
                *(float4*)&ra[0] = *(const float4*)&As[kt][ty * 8];
                *(float4*)&ra[4] = *(const float4*)&As[kt][ty * 8 + 4];
                *(float4*)&rb[0] = *(const float4*)&Bs[kt][tx * 8];
                *(float4*)&rb[4] = *(const float4*)&Bs[kt][tx * 8 + 4];
#pragma unroll
                for (int i = 0; i < 8; ++i)
#pragma unroll
                    for (int j = 0; j < 8; ++j) acc[i][j] = fmaf(ra[i], rb[j], acc[i][j]);
            }
            __syncthreads();
        }
    }

    // epilogue
    float bias[8];
#pragma unroll
    for (int j = 0; j < 8; ++j) {
        int c = col0 + tx * 8 + j;
        float b = 0.f;
        if (g.bias1) b += g.bias1[c];
        if (g.bias2) b += g.bias2[c];
        bias[j] = b;
    }
#pragma unroll
    for (int i = 0; i < 8; ++i) {
        int r = row0 + ty * 8 + i;
        if (r >= g.M) continue;
        size_t base = (size_t)r * H + col0 + tx * 8;
        float vals[8];
#pragma unroll
        for (int j = 0; j < 8; ++j) {
            float v = acc[i][j] + bias[j];
            if (g.mode == 1) v = fmaxf(v, 0.f) + g.res[base + j];
            vals[j] = v;
        }
        *reinterpret_cast<float4*>(g.out + base) = *(float4*)&vals[0];
        *reinterpret_cast<float4*>(g.out + base + 4) = *(float4*)&vals[4];
    }
}

// ---------------- row L2 normalize in place ----------------
__global__ __launch_bounds__(256) void l2norm_k(float* __restrict__ buf) {
    int row = blockIdx.x;
    size_t i = (size_t)row * H + threadIdx.x;
    float v = buf[i];
    float s = v * v;
#pragma unroll
    for (int o = 32; o > 0; o >>= 1) s += __shfl_down(s, o);
    __shared__ float partial[4];
    if ((threadIdx.x & 63) == 0) partial[threadIdx.x >> 6] = s;
    __syncthreads();
    float tot = partial[0] + partial[1] + partial[2] + partial[3];
    float n = sqrtf(tot);
    buf[i] = v / fmaxf(n, 1e-12f);
}

extern "C" void kernel_launch(void* const* d_in, const int* in_sizes, int n_in,
                              void* d_out, int out_size, void* d_ws, size_t ws_size,
                              hipStream_t stream) {
    const float* x_e = (const float*)d_in[0];
    const float* x_c = (const float*)d_in[1];
    const int* e_ee = (const int*)d_in[2];
    const int* e_ec = (const int*)d_in[3];
    const int* e_ce = (const int*)d_in[4];
    const float* P_e = (const float*)d_in[5];
    const float* P_c = (const float*)d_in[6];
    const float* Wl1 = (const float*)d_in[7];
    const float* bl1 = (const float*)d_in[8];
    const float* Wr1 = (const float*)d_in[9];
    const float* Wl2 = (const float*)d_in[10];
    const float* bl2 = (const float*)d_in[11];
    const float* Wr2 = (const float*)d_in[12];
    float* out = (float*)d_out;

    const size_t EH = (size_t)N_E * H;
    const size_t CH = (size_t)N_C * H;
    float* ws = (float*)d_ws;
    float* he0 = ws;   ws += EH;
    float* aggE1 = ws; ws += EH;
    float* aggE2 = ws; ws += EH;  // aggE1, aggE2 contiguous
    float* he1 = ws;   ws += EH;
    float* hc0 = ws;   ws += CH;
    float* aggC = ws;  ws += CH;
    float* hc1 = ws;   ws += CH;
    float* cntEE = ws; ws += N_E;
    float* cntCE = ws; ws += N_E;
    float* cntEC = ws; ws += N_C;  // counts contiguous

    const int WHH = H * H;  // weight slice stride

    // --- counts (same for both layers) ---
    hipMemsetAsync(cntEE, 0, (2 * (size_t)N_E + N_C) * sizeof(float), stream);
    count_k<<<(E_EE + 255) / 256, 256, 0, stream>>>(e_ee + E_EE, E_EE, cntEE);
    count_k<<<(E_CE + 255) / 256, 256, 0, stream>>>(e_ce + E_CE, E_CE, cntCE);
    count_k<<<(E_EC + 255) / 256, 256, 0, stream>>>(e_ec + E_EC, E_EC, cntEC);

    const dim3 gE((N_E + BM - 1) / BM, 2), gC((N_C + BM - 1) / BM, 2);

    // --- projections ---
    {
        GemmArgs g{};
        g.A[0] = x_e; g.W[0] = P_e; g.K[0] = D_E; g.nPairs = 1;
        g.out = he0; g.M = N_E; g.mode = 0;
        gemm_k<<<gE, 256, 0, stream>>>(g);
    }
    {
        GemmArgs g{};
        g.A[0] = x_c; g.W[0] = P_c; g.K[0] = D_C; g.nPairs = 1;
        g.out = hc0; g.M = N_C; g.mode = 0;
        gemm_k<<<gC, 256, 0, stream>>>(g);
    }

    // --- conv1, entity destination ---
    hipMemsetAsync(aggE1, 0, 2 * EH * sizeof(float), stream);
    scatter_k<<<(E_EE + 3) / 4, 256, 0, stream>>>(he0, e_ee, e_ee + E_EE, E_EE, aggE1);
    scatter_k<<<(E_CE + 3) / 4, 256, 0, stream>>>(hc0, e_ce, e_ce + E_CE, E_CE, aggE2);
    meandiv_k<<<N_E, 256, 0, stream>>>(aggE1, cntEE);
    meandiv_k<<<N_E, 256, 0, stream>>>(aggE2, cntCE);
    {
        GemmArgs g{};
        g.A[0] = aggE1; g.W[0] = Wl1 + 0 * WHH; g.K[0] = H;
        g.A[1] = aggE2; g.W[1] = Wl1 + 2 * WHH; g.K[1] = H;
        g.A[2] = he0;   g.W[2] = Wr1 + 0 * WHH; g.K[2] = H;
        g.A[3] = he0;   g.W[3] = Wr1 + 2 * WHH; g.K[3] = H;
        g.nPairs = 4;
        g.bias1 = bl1 + 0 * H; g.bias2 = bl1 + 2 * H;
        g.res = he0; g.out = he1; g.M = N_E; g.mode = 1;
        gemm_k<<<gE, 256, 0, stream>>>(g);
    }

    // --- conv1, chunk destination ---
    hipMemsetAsync(aggC, 0, CH * sizeof(float), stream);
    scatter_k<<<(E_EC + 3) / 4, 256, 0, stream>>>(he0, e_ec, e_ec + E_EC, E_EC, aggC);
    meandiv_k<<<N_C, 256, 0, stream>>>(aggC, cntEC);
    {
        GemmArgs g{};
        g.A[0] = aggC; g.W[0] = Wl1 + 1 * WHH; g.K[0] = H;
        g.A[1] = hc0;  g.W[1] = Wr1 + 1 * WHH; g.K[1] = H;
        g.nPairs = 2;
        g.bias1 = bl1 + 1 * H;
        g.res = hc0; g.out = hc1; g.M = N_C; g.mode = 1;
        gemm_k<<<gC, 256, 0, stream>>>(g);
    }

    // --- conv2, entity destination -> d_out[0 : N_E*H] ---
    hipMemsetAsync(aggE1, 0, 2 * EH * sizeof(float), stream);
    scatter_k<<<(E_EE + 3) / 4, 256, 0, stream>>>(he1, e_ee, e_ee + E_EE, E_EE, aggE1);
    scatter_k<<<(E_CE + 3) / 4, 256, 0, stream>>>(hc1, e_ce, e_ce + E_CE, E_CE, aggE2);
    meandiv_k<<<N_E, 256, 0, stream>>>(aggE1, cntEE);
    meandiv_k<<<N_E, 256, 0, stream>>>(aggE2, cntCE);
    {
        GemmArgs g{};
        g.A[0] = aggE1; g.W[0] = Wl2 + 0 * WHH; g.K[0] = H;
        g.A[1] = aggE2; g.W[1] = Wl2 + 2 * WHH; g.K[1] = H;
        g.A[2] = he1;   g.W[2] = Wr2 + 0 * WHH; g.K[2] = H;
        g.A[3] = he1;   g.W[3] = Wr2 + 2 * WHH; g.K[3] = H;
        g.nPairs = 4;
        g.bias1 = bl2 + 0 * H; g.bias2 = bl2 + 2 * H;
        g.out = out; g.M = N_E; g.mode = 2;
        gemm_k<<<gE, 256, 0, stream>>>(g);
    }

    // --- conv2, chunk destination -> d_out[N_E*H : ] ---
    hipMemsetAsync(aggC, 0, CH * sizeof(float), stream);
    scatter_k<<<(E_EC + 3) / 4, 256, 0, stream>>>(he1, e_ec, e_ec + E_EC, E_EC, aggC);
    meandiv_k<<<N_C, 256, 0, stream>>>(aggC, cntEC);
    {
        GemmArgs g{};
        g.A[0] = aggC; g.W[0] = Wl2 + 1 * WHH; g.K[0] = H;
        g.A[1] = hc1;  g.W[1] = Wr2 + 1 * WHH; g.K[1] = H;
        g.nPairs = 2;
        g.bias1 = bl2 + 1 * H;
        g.out = out + EH; g.M = N_C; g.mode = 2;
        gemm_k<<<gC, 256, 0, stream>>>(g);
    }

    // --- final row-wise L2 normalize, in place on d_out ---
    l2norm_k<<<N_E + N_C, 256, 0, stream>>>(out);
}

// Round 2
// 3998.730 us; speedup vs baseline: 3.4930x; 3.4930x over previous
//
#include <hip/hip_runtime.h>
#include <hip/hip_bf16.h>

#define N_E 100000
#define N_C 50000
#define H 256
#define D_E 768
#define D_C 1024
#define E_EE 800000
#define E_EC 400000
#define E_CE 400000

#define BM 128
#define BN 128
#define KT 16

// ---------------- histogram: cnt[dst]++ ----------------
__global__ __launch_bounds__(256) void hist_k(const int* __restrict__ dst, int E,
                                              int* __restrict__ cnt) {
    int i = blockIdx.x * 256 + threadIdx.x;
    if (i < E) atomicAdd(&cnt[dst[i]], 1);
}

// ---------------- single-block exclusive scan: rowptr[0..n] ----------------
__global__ __launch_bounds__(1024) void scan_k(const int* __restrict__ cnt, int n,
                                               int* __restrict__ rowptr) {
    __shared__ int smem[1024];
    __shared__ int carry;
    if (threadIdx.x == 0) carry = 0;
    __syncthreads();
    for (int base = 0; base < n; base += 1024) {
        int i = base + threadIdx.x;
        int v = (i < n) ? cnt[i] : 0;
        smem[threadIdx.x] = v;
        __syncthreads();
        for (int off = 1; off < 1024; off <<= 1) {
            int t = (threadIdx.x >= off) ? smem[threadIdx.x - off] : 0;
            __syncthreads();
            smem[threadIdx.x] += t;
            __syncthreads();
        }
        if (i < n) rowptr[i] = carry + smem[threadIdx.x] - v;  // exclusive
        __syncthreads();
        if (threadIdx.x == 1023) carry += smem[1023];
        __syncthreads();
    }
    if (threadIdx.x == 0) rowptr[n] = carry;
}

// ---------------- reorder: srcSorted[cursor[dst]++] = src ----------------
__global__ __launch_bounds__(256) void reorder_k(const int* __restrict__ src,
                                                 const int* __restrict__ dst, int E,
                                                 int* __restrict__ cursor,
                                                 int* __restrict__ srcSorted) {
    int e = blockIdx.x * 256 + threadIdx.x;
    if (e < E) {
        int pos = atomicAdd(&cursor[dst[e]], 1);
        srcSorted[pos] = src[e];
    }
}

// ---------------- gather-mean: out[r] = mean(feat[srcIdx[e]]) over r's edges ----------------
// one wave (64 lanes) per destination row; lane handles 4 consecutive floats
__global__ __launch_bounds__(256) void gather_mean_k(const float* __restrict__ feat,
                                                     const int* __restrict__ rowptr,
                                                     const int* __restrict__ srcIdx,
                                                     int nDst,
                                                     float* __restrict__ outAgg) {
    int r = blockIdx.x * 4 + (threadIdx.x >> 6);
    if (r >= nDst) return;
    int lane = threadIdx.x & 63;
    int e0 = rowptr[r], e1 = rowptr[r + 1];
    float4 acc = make_float4(0.f, 0.f, 0.f, 0.f);
    for (int e = e0; e < e1; ++e) {
        int s = srcIdx[e];
        const float4 v = *reinterpret_cast<const float4*>(feat + (size_t)s * H + lane * 4);
        acc.x += v.x; acc.y += v.y; acc.z += v.z; acc.w += v.w;
    }
    float inv = (e1 > e0) ? 1.0f / (float)(e1 - e0) : 0.f;  // isolated -> 0
    float4 o = make_float4(acc.x * inv, acc.y * inv, acc.z * inv, acc.w * inv);
    *reinterpret_cast<float4*>(outAgg + (size_t)r * H + lane * 4) = o;
}

// ---------------- fused GEMM: out = sum_p A_p @ W_p  (+bias) (+relu+res) ----------------
struct GemmArgs {
    const float* A[4];
    const float* W[4];
    int K[4];
    int nPairs;
    const float* bias1;  // nullable
    const float* bias2;  // nullable
    const float* res;    // residual input (mode 1)
    float* out;
    int M;
    int mode;  // 0 = plain, 1 = relu(acc+bias)+res, 2 = acc+bias (pre-norm)
};

__global__ __launch_bounds__(256) void gemm_k(GemmArgs g) {
    __shared__ float As[KT][BM];
    __shared__ float Bs[KT][BN];
    const int tid = threadIdx.x;
    const int tx = tid & 15;
    const int ty = tid >> 4;
    const int row0 = blockIdx.x * BM;
    const int col0 = blockIdx.y * BN;

    float acc[8][8] = {};

    for (int p = 0; p < g.nPairs; ++p) {
        const float* __restrict__ A = g.A[p];
        const float* __restrict__ W = g.W[p];
        const int K = g.K[p];
        for (int k0 = 0; k0 < K; k0 += KT) {
#pragma unroll
            for (int i = 0; i < 2; ++i) {
                int f = tid * 2 + i;
                int r = f >> 2;
                int kq = f & 3;
                int grow = row0 + r;
                float4 v = make_float4(0.f, 0.f, 0.f, 0.f);
                if (grow < g.M)
                    v = *reinterpret_cast<const float4*>(A + (size_t)grow * K + k0 + kq * 4);
                As[kq * 4 + 0][r] = v.x;
                As[kq * 4 + 1][r] = v.y;
                As[kq * 4 + 2][r] = v.z;
                As[kq * 4 + 3][r] = v.w;
            }
#pragma unroll
            for (int i = 0; i < 2; ++i) {
                int f = tid * 2 + i;
                int kr = f >> 5;
                int cq = f & 31;
                *reinterpret_cast<float4*>(&Bs[kr][cq * 4]) =
                    *reinterpret_cast<const float4*>(W + (size_t)(k0 + kr) * H + col0 + cq * 4);
            }
            __syncthreads();
#pragma unroll
            for (int kt = 0; kt < KT; ++kt) {
                float ra[8], rb[8];
                *(float4*)&ra[0] = *(const float4*)&As[kt][ty * 8];
                *(float4*)&ra[4] = *(const float4*)&As[kt][ty * 8 + 4];
                *(float4*)&rb[0] = *(const float4*)&Bs[kt][tx * 8];
                *(float4*)&rb[4] = *(const float4*)&Bs[kt][tx * 8 + 4];
#pragma unroll
                for (int i = 0; i < 8; ++i)
#pragma unroll
                    for (int j = 0; j < 8; ++j) acc[i][j] = fmaf(ra[i], rb[j], acc[i][j]);
            }
            __syncthreads();
        }
    }

    float bias[8];
#pragma unroll
    for (int j = 0; j < 8; ++j) {
        int c = col0 + tx * 8 + j;
        float b = 0.f;
        if (g.bias1) b += g.bias1[c];
        if (g.bias2) b += g.bias2[c];
        bias[j] = b;
    }
#pragma unroll
    for (int i = 0; i < 8; ++i) {
        int r = row0 + ty * 8 + i;
        if (r >= g.M) continue;
        size_t base = (size_t)r * H + col0 + tx * 8;
        float vals[8];
#pragma unroll
        for (int j = 0; j < 8; ++j) {
            float v = acc[i][j] + bias[j];
            if (g.mode == 1) v = fmaxf(v, 0.f) + g.res[base + j];
            vals[j] = v;
        }
        *reinterpret_cast<float4*>(g.out + base) = *(float4*)&vals[0];
        *reinterpret_cast<float4*>(g.out + base + 4) = *(float4*)&vals[4];
    }
}

// ---------------- row L2 normalize in place ----------------
__global__ __launch_bounds__(256) void l2norm_k(float* __restrict__ buf) {
    int row = blockIdx.x;
    size_t i = (size_t)row * H + threadIdx.x;
    float v = buf[i];
    float s = v * v;
#pragma unroll
    for (int o = 32; o > 0; o >>= 1) s += __shfl_down(s, o);
    __shared__ float partial[4];
    if ((threadIdx.x & 63) == 0) partial[threadIdx.x >> 6] = s;
    __syncthreads();
    float tot = partial[0] + partial[1] + partial[2] + partial[3];
    float n = sqrtf(tot);
    buf[i] = v / fmaxf(n, 1e-12f);
}

// helper: build CSR for one edge type
static void build_csr(const int* src, const int* dst, int E, int nDst,
                      int* cur, int* rowptr, int* srcSorted, hipStream_t stream) {
    hipMemsetAsync(cur, 0, (size_t)nDst * sizeof(int), stream);
    hist_k<<<(E + 255) / 256, 256, 0, stream>>>(dst, E, cur);
    scan_k<<<1, 1024, 0, stream>>>(cur, nDst, rowptr);
    hipMemcpyAsync(cur, rowptr, (size_t)nDst * sizeof(int), hipMemcpyDeviceToDevice, stream);
    reorder_k<<<(E + 255) / 256, 256, 0, stream>>>(src, dst, E, cur, srcSorted);
}

extern "C" void kernel_launch(void* const* d_in, const int* in_sizes, int n_in,
                              void* d_out, int out_size, void* d_ws, size_t ws_size,
                              hipStream_t stream) {
    const float* x_e = (const float*)d_in[0];
    const float* x_c = (const float*)d_in[1];
    const int* e_ee = (const int*)d_in[2];
    const int* e_ec = (const int*)d_in[3];
    const int* e_ce = (const int*)d_in[4];
    const float* P_e = (const float*)d_in[5];
    const float* P_c = (const float*)d_in[6];
    const float* Wl1 = (const float*)d_in[7];
    const float* bl1 = (const float*)d_in[8];
    const float* Wr1 = (const float*)d_in[9];
    const float* Wl2 = (const float*)d_in[10];
    const float* bl2 = (const float*)d_in[11];
    const float* Wr2 = (const float*)d_in[12];
    float* out = (float*)d_out;

    const size_t EH = (size_t)N_E * H;
    const size_t CH = (size_t)N_C * H;
    float* ws = (float*)d_ws;
    float* he0 = ws;   ws += EH;
    float* aggE1 = ws; ws += EH;
    float* aggE2 = ws; ws += EH;
    float* he1 = ws;   ws += EH;
    float* hc0 = ws;   ws += CH;
    float* aggC = ws;  ws += CH;
    float* hc1 = ws;   ws += CH;
    // int region for 3 CSRs
    int* ip = (int*)ws;
    int* eePtr = ip;  ip += N_E + 1;
    int* eeSrc = ip;  ip += E_EE;
    int* eeCur = ip;  ip += N_E;
    int* cePtr = ip;  ip += N_E + 1;
    int* ceSrc = ip;  ip += E_CE;
    int* ceCur = ip;  ip += N_E;
    int* ecPtr = ip;  ip += N_C + 1;
    int* ecSrc = ip;  ip += E_EC;
    int* ecCur = ip;  ip += N_C;

    const int WHH = H * H;

    // --- build CSR once per call (both layers reuse) ---
    build_csr(e_ee, e_ee + E_EE, E_EE, N_E, eeCur, eePtr, eeSrc, stream);
    build_csr(e_ce, e_ce + E_CE, E_CE, N_E, ceCur, cePtr, ceSrc, stream);
    build_csr(e_ec, e_ec + E_EC, E_EC, N_C, ecCur, ecPtr, ecSrc, stream);

    const dim3 gE((N_E + BM - 1) / BM, 2), gC((N_C + BM - 1) / BM, 2);

    // --- projections ---
    {
        GemmArgs g{};
        g.A[0] = x_e; g.W[0] = P_e; g.K[0] = D_E; g.nPairs = 1;
        g.out = he0; g.M = N_E; g.mode = 0;
        gemm_k<<<gE, 256, 0, stream>>>(g);
    }
    {
        GemmArgs g{};
        g.A[0] = x_c; g.W[0] = P_c; g.K[0] = D_C; g.nPairs = 1;
        g.out = hc0; g.M = N_C; g.mode = 0;
        gemm_k<<<gC, 256, 0, stream>>>(g);
    }

    // --- conv1, entity destination ---
    gather_mean_k<<<(N_E + 3) / 4, 256, 0, stream>>>(he0, eePtr, eeSrc, N_E, aggE1);
    gather_mean_k<<<(N_E + 3) / 4, 256, 0, stream>>>(hc0, cePtr, ceSrc, N_E, aggE2);
    {
        GemmArgs g{};
        g.A[0] = aggE1; g.W[0] = Wl1 + 0 * WHH; g.K[0] = H;
        g.A[1] = aggE2; g.W[1] = Wl1 + 2 * WHH; g.K[1] = H;
        g.A[2] = he0;   g.W[2] = Wr1 + 0 * WHH; g.K[2] = H;
        g.A[3] = he0;   g.W[3] = Wr1 + 2 * WHH; g.K[3] = H;
        g.nPairs = 4;
        g.bias1 = bl1 + 0 * H; g.bias2 = bl1 + 2 * H;
        g.res = he0; g.out = he1; g.M = N_E; g.mode = 1;
        gemm_k<<<gE, 256, 0, stream>>>(g);
    }

    // --- conv1, chunk destination ---
    gather_mean_k<<<(N_C + 3) / 4, 256, 0, stream>>>(he0, ecPtr, ecSrc, N_C, aggC);
    {
        GemmArgs g{};
        g.A[0] = aggC; g.W[0] = Wl1 + 1 * WHH; g.K[0] = H;
        g.A[1] = hc0;  g.W[1] = Wr1 + 1 * WHH; g.K[1] = H;
        g.nPairs = 2;
        g.bias1 = bl1 + 1 * H;
        g.res = hc0; g.out = hc1; g.M = N_C; g.mode = 1;
        gemm_k<<<gC, 256, 0, stream>>>(g);
    }

    // --- conv2, entity destination -> d_out ---
    gather_mean_k<<<(N_E + 3) / 4, 256, 0, stream>>>(he1, eePtr, eeSrc, N_E, aggE1);
    gather_mean_k<<<(N_E + 3) / 4, 256, 0, stream>>>(hc1, cePtr, ceSrc, N_E, aggE2);
    {
        GemmArgs g{};
        g.A[0] = aggE1; g.W[0] = Wl2 + 0 * WHH; g.K[0] = H;
        g.A[1] = aggE2; g.W[1] = Wl2 + 2 * WHH; g.K[1] = H;
        g.A[2] = he1;   g.W[2] = Wr2 + 0 * WHH; g.K[2] = H;
        g.A[3] = he1;   g.W[3] = Wr2 + 2 * WHH; g.K[3] = H;
        g.nPairs = 4;
        g.bias1 = bl2 + 0 * H; g.bias2 = bl2 + 2 * H;
        g.out = out; g.M = N_E; g.mode = 2;
        gemm_k<<<gE, 256, 0, stream>>>(g);
    }

    // --- conv2, chunk destination -> d_out[N_E*H:] ---
    gather_mean_k<<<(N_C + 3) / 4, 256, 0, stream>>>(he1, ecPtr, ecSrc, N_C, aggC);
    {
        GemmArgs g{};
        g.A[0] = aggC; g.W[0] = Wl2 + 1 * WHH; g.K[0] = H;
        g.A[1] = hc1;  g.W[1] = Wr2 + 1 * WHH; g.K[1] = H;
        g.nPairs = 2;
        g.bias1 = bl2 + 1 * H;
        g.out = out + EH; g.M = N_C; g.mode = 2;
        gemm_k<<<gC, 256, 0, stream>>>(g);
    }

    // --- final row-wise L2 normalize, in place on d_out ---
    l2norm_k<<<N_E + N_C, 256, 0, stream>>>(out);
}

// Round 3
// 2022.769 us; speedup vs baseline: 6.9051x; 1.9769x over previous
//
#include <hip/hip_runtime.h>
#include <hip/hip_bf16.h>

#define N_E 100000
#define N_C 50000
#define H 256
#define D_E 768
#define D_C 1024
#define E_EE 800000
#define E_EC 400000
#define E_CE 400000

#define ME_PAD 100096  // 782*128
#define MC_PAD 50048   // 391*128

typedef unsigned short u16;
typedef __attribute__((ext_vector_type(8))) short bf16x8;
typedef __attribute__((ext_vector_type(4))) float f32x4;

__device__ __forceinline__ float bf2f(u16 x) {
    unsigned u = ((unsigned)x) << 16;
    return __builtin_bit_cast(float, u);
}
__device__ __forceinline__ u16 f2bf(float f) {
    unsigned u = __builtin_bit_cast(unsigned, f);
    u = (u + 0x7fffu + ((u >> 16) & 1u)) >> 16;
    return (u16)u;
}

// ---------------- fp32 -> bf16 convert with row padding ----------------
__global__ __launch_bounds__(256) void cvt_pad_k(const float* __restrict__ in,
                                                 u16* __restrict__ out, int M, int K) {
    int r = blockIdx.x;  // 0..Mpad-1
    bool valid = r < M;
    for (int c = threadIdx.x * 4; c < K; c += 1024) {
        float4 v = make_float4(0.f, 0.f, 0.f, 0.f);
        if (valid) v = *reinterpret_cast<const float4*>(in + (size_t)r * K + c);
        ushort4 o;
        o.x = f2bf(v.x); o.y = f2bf(v.y); o.z = f2bf(v.z); o.w = f2bf(v.w);
        *reinterpret_cast<ushort4*>(out + (size_t)r * K + c) = o;
    }
}

// ---------------- weight transpose: in [K][256] fp32 -> out [256][K] bf16 ----------------
__global__ __launch_bounds__(1024) void transpose_w_k(const float* __restrict__ in,
                                                      u16* __restrict__ out, int K) {
    __shared__ float t[32][33];
    int k0 = blockIdx.x * 32, n0 = blockIdx.y * 32;
    int tx = threadIdx.x, ty = threadIdx.y;
    t[ty][tx] = in[(size_t)(k0 + ty) * H + n0 + tx];
    __syncthreads();
    out[(size_t)(n0 + ty) * K + k0 + tx] = f2bf(t[tx][ty]);
}

// ---------------- CSR build ----------------
__global__ __launch_bounds__(256) void hist_k(const int* __restrict__ dst, int E,
                                              int* __restrict__ cnt) {
    int i = blockIdx.x * 256 + threadIdx.x;
    if (i < E) atomicAdd(&cnt[dst[i]], 1);
}

__global__ __launch_bounds__(1024) void scan_k(const int* __restrict__ cnt, int n,
                                               int* __restrict__ rowptr) {
    __shared__ int smem[1024];
    __shared__ int carry;
    if (threadIdx.x == 0) carry = 0;
    __syncthreads();
    for (int base = 0; base < n; base += 1024) {
        int i = base + threadIdx.x;
        int v = (i < n) ? cnt[i] : 0;
        smem[threadIdx.x] = v;
        __syncthreads();
        for (int off = 1; off < 1024; off <<= 1) {
            int t = (threadIdx.x >= off) ? smem[threadIdx.x - off] : 0;
            __syncthreads();
            smem[threadIdx.x] += t;
            __syncthreads();
        }
        if (i < n) rowptr[i] = carry + smem[threadIdx.x] - v;
        __syncthreads();
        if (threadIdx.x == 1023) carry += smem[1023];
        __syncthreads();
    }
    if (threadIdx.x == 0) rowptr[n] = carry;
}

__global__ __launch_bounds__(256) void reorder_k(const int* __restrict__ src,
                                                 const int* __restrict__ dst, int E,
                                                 int* __restrict__ cursor,
                                                 int* __restrict__ srcSorted) {
    int e = blockIdx.x * 256 + threadIdx.x;
    if (e < E) {
        int pos = atomicAdd(&cursor[dst[e]], 1);
        srcSorted[pos] = src[e];
    }
}

// ---------------- gather-mean over bf16 features ----------------
__global__ __launch_bounds__(256) void gather_mean_k(const u16* __restrict__ feat,
                                                     const int* __restrict__ rowptr,
                                                     const int* __restrict__ srcIdx,
                                                     int nDst, int nPad,
                                                     u16* __restrict__ outAgg) {
    int r = blockIdx.x * 4 + (threadIdx.x >> 6);
    if (r >= nPad) return;
    int lane = threadIdx.x & 63;
    float ax = 0.f, ay = 0.f, az = 0.f, aw = 0.f;
    int deg = 0;
    if (r < nDst) {
        int e0 = rowptr[r], e1 = rowptr[r + 1];
        deg = e1 - e0;
        for (int e = e0; e < e1; ++e) {
            int s = srcIdx[e];
            ushort4 v = *reinterpret_cast<const ushort4*>(feat + (size_t)s * H + lane * 4);
            ax += bf2f(v.x); ay += bf2f(v.y); az += bf2f(v.z); aw += bf2f(v.w);
        }
    }
    float inv = deg > 0 ? 1.f / (float)deg : 0.f;
    ushort4 o;
    o.x = f2bf(ax * inv); o.y = f2bf(ay * inv); o.z = f2bf(az * inv); o.w = f2bf(aw * inv);
    *reinterpret_cast<ushort4*>(outAgg + (size_t)r * H + lane * 4) = o;
}

// ---------------- bf16 MFMA GEMM: out = sum_p A_p @ Wt_p^T (+bias)(+relu+res) ----------------
// A_p: [Mpad][K_p] bf16 row-major (padded). Wt_p: [256][K_p] bf16 (transposed weight).
// Block: 512 threads (8 waves, 2x4), tile 128 rows x 256 cols. BK=32.
struct GemmArgs {
    const u16* A[4];
    const u16* Wt[4];
    int K[4];
    int nPairs;
    const float* bias1;  // nullable
    const float* bias2;  // nullable
    const u16* res;      // bf16 residual (mode 1)
    void* out;           // u16 (mode 0/1) or float (mode 2)
    int mode;
};

__global__ __launch_bounds__(512) void gemm_bf16_k(GemmArgs g) {
    __shared__ u16 Asmem[128 * 32];  // [row][32 k], 64B rows, units swizzled
    const int tid = threadIdx.x;
    const int lane = tid & 63;
    const int wid = tid >> 6;   // 0..7
    const int wm = wid >> 2;    // 0..1
    const int wn = wid & 3;     // 0..3
    const int row0 = blockIdx.x * 128;

    f32x4 acc[4][4] = {};

    // staging geometry: wave w stages rows [w*16, w*16+16)
    const int s_rl = wid * 16 + (lane >> 2);       // local row
    const int s_usw = (lane & 3) ^ ((s_rl >> 1) & 3);  // pre-swizzled 16B source unit

    // A-fragment ds_read byte offsets (constant across K-steps; single LDS buffer)
    int a_off[4];
#pragma unroll
    for (int mi = 0; mi < 4; ++mi) {
        int rl = wm * 64 + mi * 16 + (lane & 15);
        int u = (lane >> 4) ^ ((rl >> 1) & 3);
        a_off[mi] = rl * 64 + u * 16;
    }

    for (int p = 0; p < g.nPairs; ++p) {
        const int K = g.K[p];
        const u16* Abase = g.A[p] + (size_t)(row0 + s_rl) * K + s_usw * 8;
        const u16* Wbase = g.Wt[p] + (size_t)(wn * 64 + (lane & 15)) * K + (lane >> 4) * 8;
        for (int k0 = 0; k0 < K; k0 += 32) {
            __syncthreads();  // previous compute finished reading LDS
            __builtin_amdgcn_global_load_lds(
                (const __attribute__((address_space(1))) void*)(Abase + k0),
                (__attribute__((address_space(3))) void*)(Asmem + wid * 512), 16, 0, 0);
            __syncthreads();  // compiler drains vmcnt before barrier -> tile ready
            bf16x8 bfrag[4], afrag[4];
#pragma unroll
            for (int ni = 0; ni < 4; ++ni)
                bfrag[ni] = *reinterpret_cast<const bf16x8*>(Wbase + (size_t)(ni * 16) * K + k0);
#pragma unroll
            for (int mi = 0; mi < 4; ++mi)
                afrag[mi] = *reinterpret_cast<bf16x8*>((char*)Asmem + a_off[mi]);
#pragma unroll
            for (int mi = 0; mi < 4; ++mi)
#pragma unroll
                for (int ni = 0; ni < 4; ++ni)
                    acc[mi][ni] = __builtin_amdgcn_mfma_f32_16x16x32_bf16(
                        afrag[mi], bfrag[ni], acc[mi][ni], 0, 0, 0);
        }
    }

    // epilogue: D lane mapping col = lane&15, row = (lane>>4)*4 + j  [m89/m91]
    const int ccol = wn * 64 + (lane & 15);
    const int crow0 = row0 + wm * 64 + ((lane >> 4) << 2);
#pragma unroll
    for (int ni = 0; ni < 4; ++ni) {
        int c = ccol + ni * 16;
        float bv = 0.f;
        if (g.bias1) bv += g.bias1[c];
        if (g.bias2) bv += g.bias2[c];
#pragma unroll
        for (int mi = 0; mi < 4; ++mi) {
#pragma unroll
            for (int j = 0; j < 4; ++j) {
                int r = crow0 + mi * 16 + j;
                size_t idx = (size_t)r * H + c;
                float v = acc[mi][ni][j] + bv;
                if (g.mode == 1) {
                    v = fmaxf(v, 0.f) + bf2f(g.res[idx]);
                    ((u16*)g.out)[idx] = f2bf(v);
                } else if (g.mode == 0) {
                    ((u16*)g.out)[idx] = f2bf(v);
                } else {
                    ((float*)g.out)[idx] = v;
                }
            }
        }
    }
}

// ---------------- row L2 normalize: padded fp32 src -> d_out ----------------
__global__ __launch_bounds__(256) void l2norm_k(const float* __restrict__ srcE,
                                                const float* __restrict__ srcC,
                                                float* __restrict__ out) {
    int row = blockIdx.x;
    const float* src = (row < N_E) ? (srcE + (size_t)row * H)
                                   : (srcC + (size_t)(row - N_E) * H);
    float v = src[threadIdx.x];
    float s = v * v;
#pragma unroll
    for (int o = 32; o > 0; o >>= 1) s += __shfl_down(s, o);
    __shared__ float partial[4];
    if ((threadIdx.x & 63) == 0) partial[threadIdx.x >> 6] = s;
    __syncthreads();
    float tot = partial[0] + partial[1] + partial[2] + partial[3];
    float n = sqrtf(tot);
    out[(size_t)row * H + threadIdx.x] = v / fmaxf(n, 1e-12f);
}

static void build_csr(const int* src, const int* dst, int E, int nDst,
                      int* cur, int* rowptr, int* srcSorted, hipStream_t stream) {
    hipMemsetAsync(cur, 0, (size_t)nDst * sizeof(int), stream);
    hist_k<<<(E + 255) / 256, 256, 0, stream>>>(dst, E, cur);
    scan_k<<<1, 1024, 0, stream>>>(cur, nDst, rowptr);
    hipMemcpyAsync(cur, rowptr, (size_t)nDst * sizeof(int), hipMemcpyDeviceToDevice, stream);
    reorder_k<<<(E + 255) / 256, 256, 0, stream>>>(src, dst, E, cur, srcSorted);
}

extern "C" void kernel_launch(void* const* d_in, const int* in_sizes, int n_in,
                              void* d_out, int out_size, void* d_ws, size_t ws_size,
                              hipStream_t stream) {
    const float* x_e = (const float*)d_in[0];
    const float* x_c = (const float*)d_in[1];
    const int* e_ee = (const int*)d_in[2];
    const int* e_ec = (const int*)d_in[3];
    const int* e_ce = (const int*)d_in[4];
    const float* P_e = (const float*)d_in[5];
    const float* P_c = (const float*)d_in[6];
    const float* Wl1 = (const float*)d_in[7];
    const float* bl1 = (const float*)d_in[8];
    const float* Wr1 = (const float*)d_in[9];
    const float* Wl2 = (const float*)d_in[10];
    const float* bl2 = (const float*)d_in[11];
    const float* Wr2 = (const float*)d_in[12];
    float* out = (float*)d_out;

    const size_t EHp = (size_t)ME_PAD * H;
    const size_t CHp = (size_t)MC_PAD * H;

    u16* us = (u16*)d_ws;
    u16* x_eb = us;  us += (size_t)ME_PAD * D_E;
    u16* x_cb = us;  us += (size_t)MC_PAD * D_C;
    u16* he0 = us;   us += EHp;
    u16* he1 = us;   us += EHp;
    u16* aggE1 = us; us += EHp;
    u16* aggE2 = us; us += EHp;
    u16* hc0 = us;   us += CHp;
    u16* hc1 = us;   us += CHp;
    u16* aggC = us;  us += CHp;
    u16* PeT = us;   us += H * D_E;
    u16* PcT = us;   us += H * D_C;
    u16* WlT1 = us;  us += 3 * H * H;
    u16* WrT1 = us;  us += 3 * H * H;
    u16* WlT2 = us;  us += 3 * H * H;
    u16* WrT2 = us;  us += 3 * H * H;
    // fp32 conv2 outputs overlay the (then-dead) x_eb / x_cb regions
    float* opadE = (float*)x_eb;  // needs ME_PAD*H*4B <= ME_PAD*D_E*2B  (768*2 > 256*4) OK
    float* opadC = (float*)x_cb;  // MC_PAD*H*4B <= MC_PAD*D_C*2B OK

    int* ip = (int*)us;
    int* eePtr = ip;  ip += N_E + 1;
    int* eeSrc = ip;  ip += E_EE;
    int* eeCur = ip;  ip += N_E;
    int* cePtr = ip;  ip += N_E + 1;
    int* ceSrc = ip;  ip += E_CE;
    int* ceCur = ip;  ip += N_E;
    int* ecPtr = ip;  ip += N_C + 1;
    int* ecSrc = ip;  ip += E_EC;
    int* ecCur = ip;  ip += N_C;

    const int WHH = H * H;

    // --- CSR (reused by both layers) ---
    build_csr(e_ee, e_ee + E_EE, E_EE, N_E, eeCur, eePtr, eeSrc, stream);
    build_csr(e_ce, e_ce + E_CE, E_CE, N_E, ceCur, cePtr, ceSrc, stream);
    build_csr(e_ec, e_ec + E_EC, E_EC, N_C, ecCur, ecPtr, ecSrc, stream);

    // --- bf16 conversions ---
    cvt_pad_k<<<ME_PAD, 256, 0, stream>>>(x_e, x_eb, N_E, D_E);
    cvt_pad_k<<<MC_PAD, 256, 0, stream>>>(x_c, x_cb, N_C, D_C);
    {
        dim3 blk(32, 32);
        transpose_w_k<<<dim3(D_E / 32, H / 32), blk, 0, stream>>>(P_e, PeT, D_E);
        transpose_w_k<<<dim3(D_C / 32, H / 32), blk, 0, stream>>>(P_c, PcT, D_C);
        for (int p = 0; p < 3; ++p) {
            transpose_w_k<<<dim3(H / 32, H / 32), blk, 0, stream>>>(Wl1 + p * WHH, WlT1 + p * WHH, H);
            transpose_w_k<<<dim3(H / 32, H / 32), blk, 0, stream>>>(Wr1 + p * WHH, WrT1 + p * WHH, H);
            transpose_w_k<<<dim3(H / 32, H / 32), blk, 0, stream>>>(Wl2 + p * WHH, WlT2 + p * WHH, H);
            transpose_w_k<<<dim3(H / 32, H / 32), blk, 0, stream>>>(Wr2 + p * WHH, WrT2 + p * WHH, H);
        }
    }

    const int gridE = ME_PAD / 128, gridC = MC_PAD / 128;

    // --- projections ---
    {
        GemmArgs g{};
        g.A[0] = x_eb; g.Wt[0] = PeT; g.K[0] = D_E; g.nPairs = 1;
        g.out = he0; g.mode = 0;
        gemm_bf16_k<<<gridE, 512, 0, stream>>>(g);
    }
    {
        GemmArgs g{};
        g.A[0] = x_cb; g.Wt[0] = PcT; g.K[0] = D_C; g.nPairs = 1;
        g.out = hc0; g.mode = 0;
        gemm_bf16_k<<<gridC, 512, 0, stream>>>(g);
    }

    // --- conv1 ---
    gather_mean_k<<<ME_PAD / 4, 256, 0, stream>>>(he0, eePtr, eeSrc, N_E, ME_PAD, aggE1);
    gather_mean_k<<<ME_PAD / 4, 256, 0, stream>>>(hc0, cePtr, ceSrc, N_E, ME_PAD, aggE2);
    gather_mean_k<<<MC_PAD / 4, 256, 0, stream>>>(he0, ecPtr, ecSrc, N_C, MC_PAD, aggC);
    {
        GemmArgs g{};
        g.A[0] = aggE1; g.Wt[0] = WlT1 + 0 * WHH; g.K[0] = H;
        g.A[1] = aggE2; g.Wt[1] = WlT1 + 2 * WHH; g.K[1] = H;
        g.A[2] = he0;   g.Wt[2] = WrT1 + 0 * WHH; g.K[2] = H;
        g.A[3] = he0;   g.Wt[3] = WrT1 + 2 * WHH; g.K[3] = H;
        g.nPairs = 4;
        g.bias1 = bl1 + 0 * H; g.bias2 = bl1 + 2 * H;
        g.res = he0; g.out = he1; g.mode = 1;
        gemm_bf16_k<<<gridE, 512, 0, stream>>>(g);
    }
    {
        GemmArgs g{};
        g.A[0] = aggC; g.Wt[0] = WlT1 + 1 * WHH; g.K[0] = H;
        g.A[1] = hc0;  g.Wt[1] = WrT1 + 1 * WHH; g.K[1] = H;
        g.nPairs = 2;
        g.bias1 = bl1 + 1 * H;
        g.res = hc0; g.out = hc1; g.mode = 1;
        gemm_bf16_k<<<gridC, 512, 0, stream>>>(g);
    }

    // --- conv2 ---
    gather_mean_k<<<ME_PAD / 4, 256, 0, stream>>>(he1, eePtr, eeSrc, N_E, ME_PAD, aggE1);
    gather_mean_k<<<ME_PAD / 4, 256, 0, stream>>>(hc1, cePtr, ceSrc, N_E, ME_PAD, aggE2);
    gather_mean_k<<<MC_PAD / 4, 256, 0, stream>>>(he1, ecPtr, ecSrc, N_C, MC_PAD, aggC);
    {
        GemmArgs g{};
        g.A[0] = aggE1; g.Wt[0] = WlT2 + 0 * WHH; g.K[0] = H;
        g.A[1] = aggE2; g.Wt[1] = WlT2 + 2 * WHH; g.K[1] = H;
        g.A[2] = he1;   g.Wt[2] = WrT2 + 0 * WHH; g.K[2] = H;
        g.A[3] = he1;   g.Wt[3] = WrT2 + 2 * WHH; g.K[3] = H;
        g.nPairs = 4;
        g.bias1 = bl2 + 0 * H; g.bias2 = bl2 + 2 * H;
        g.out = opadE; g.mode = 2;
        gemm_bf16_k<<<gridE, 512, 0, stream>>>(g);
    }
    {
        GemmArgs g{};
        g.A[0] = aggC; g.Wt[0] = WlT2 + 1 * WHH; g.K[0] = H;
        g.A[1] = hc1;  g.Wt[1] = WrT2 + 1 * WHH; g.K[1] = H;
        g.nPairs = 2;
        g.bias1 = bl2 + 1 * H;
        g.out = opadC; g.mode = 2;
        gemm_bf16_k<<<gridC, 512, 0, stream>>>(g);
    }

    // --- final row-wise L2 normalize -> d_out ---
    l2norm_k<<<N_E + N_C, 256, 0, stream>>>(opadE, opadC, out);
}

// Round 4
// 1209.273 us; speedup vs baseline: 11.5503x; 1.6727x over previous
//
#include <hip/hip_runtime.h>
#include <hip/hip_bf16.h>

#define N_E 100000
#define N_C 50000
#define H 256
#define D_E 768
#define D_C 1024
#define E_EE 800000
#define E_EC 400000
#define E_CE 400000

#define ME_PAD 100096  // 782*128
#define MC_PAD 50048   // 391*128

typedef unsigned short u16;
typedef __attribute__((ext_vector_type(8))) short bf16x8;
typedef __attribute__((ext_vector_type(4))) float f32x4;

__device__ __forceinline__ float bf2f(u16 x) {
    unsigned u = ((unsigned)x) << 16;
    return __builtin_bit_cast(float, u);
}
__device__ __forceinline__ u16 f2bf(float f) {
    unsigned u = __builtin_bit_cast(unsigned, f);
    u = (u + 0x7fffu + ((u >> 16) & 1u)) >> 16;
    return (u16)u;
}

// ---------------- fp32 -> bf16 convert with row padding ----------------
__global__ __launch_bounds__(256) void cvt_pad_k(const float* __restrict__ in,
                                                 u16* __restrict__ out, int M, int K) {
    int r = blockIdx.x;
    bool valid = r < M;
    for (int c = threadIdx.x * 4; c < K; c += 1024) {
        float4 v = make_float4(0.f, 0.f, 0.f, 0.f);
        if (valid) v = *reinterpret_cast<const float4*>(in + (size_t)r * K + c);
        ushort4 o;
        o.x = f2bf(v.x); o.y = f2bf(v.y); o.z = f2bf(v.z); o.w = f2bf(v.w);
        *reinterpret_cast<ushort4*>(out + (size_t)r * K + c) = o;
    }
}

// ---------------- weight transpose: in [K][256] fp32 -> out [256][K] bf16 ----------------
__global__ __launch_bounds__(1024) void transpose_w_k(const float* __restrict__ in,
                                                      u16* __restrict__ out, int K) {
    __shared__ float t[32][33];
    int k0 = blockIdx.x * 32, n0 = blockIdx.y * 32;
    int tx = threadIdx.x, ty = threadIdx.y;
    t[ty][tx] = in[(size_t)(k0 + ty) * H + n0 + tx];
    __syncthreads();
    out[(size_t)(n0 + ty) * K + k0 + tx] = f2bf(t[tx][ty]);
}

// ---------------- CSR build: combined histogram + hierarchical scan ----------------
__global__ __launch_bounds__(256) void hist_k(const int* __restrict__ dst, int E,
                                              int* __restrict__ cnt) {
    int i = blockIdx.x * 256 + threadIdx.x;
    if (i < E) atomicAdd(&cnt[dst[i]], 1);
}

#define SCAN_N (2 * N_E + N_C)  // 250000
#define SCAN_NB ((SCAN_N + 1023) / 1024)

__global__ __launch_bounds__(1024) void scan_blk_k(const int* __restrict__ cnt,
                                                   int* __restrict__ part,
                                                   int* __restrict__ bsum) {
    __shared__ int sm[1024];
    int i = blockIdx.x * 1024 + threadIdx.x;
    int v = (i < SCAN_N) ? cnt[i] : 0;
    sm[threadIdx.x] = v;
    __syncthreads();
    for (int off = 1; off < 1024; off <<= 1) {
        int t = (threadIdx.x >= off) ? sm[threadIdx.x - off] : 0;
        __syncthreads();
        sm[threadIdx.x] += t;
        __syncthreads();
    }
    if (i < SCAN_N) part[i] = sm[threadIdx.x] - v;  // exclusive within block
    if (threadIdx.x == 1023) bsum[blockIdx.x] = sm[1023];
}

__global__ __launch_bounds__(1024) void scan_top_k(int* __restrict__ bsum) {
    __shared__ int sm[1024];
    int v = (threadIdx.x < SCAN_NB) ? bsum[threadIdx.x] : 0;
    sm[threadIdx.x] = v;
    __syncthreads();
    for (int off = 1; off < 1024; off <<= 1) {
        int t = (threadIdx.x >= off) ? sm[threadIdx.x - off] : 0;
        __syncthreads();
        sm[threadIdx.x] += t;
        __syncthreads();
    }
    if (threadIdx.x < SCAN_NB) bsum[threadIdx.x] = sm[threadIdx.x] - v;  // exclusive
}

__global__ __launch_bounds__(1024) void scan_out_k(const int* __restrict__ part,
                                                   const int* __restrict__ bsum,
                                                   int* __restrict__ eePtr, int* __restrict__ eeCur,
                                                   int* __restrict__ cePtr, int* __restrict__ ceCur,
                                                   int* __restrict__ ecPtr, int* __restrict__ ecCur) {
    int i = blockIdx.x * 1024 + threadIdx.x;
    if (i < SCAN_N) {
        int v = part[i] + bsum[blockIdx.x];
        if (i < N_E) {
            eePtr[i] = v; eeCur[i] = v;
        } else if (i < 2 * N_E) {
            int j = i - N_E, w = v - E_EE;
            cePtr[j] = w; ceCur[j] = w;
        } else {
            int j = i - 2 * N_E, w = v - (E_EE + E_CE);
            ecPtr[j] = w; ecCur[j] = w;
        }
    }
    if (i == 0) {
        eePtr[N_E] = E_EE;
        cePtr[N_E] = E_CE;
        ecPtr[N_C] = E_EC;
    }
}

__global__ __launch_bounds__(256) void reorder_k(const int* __restrict__ src,
                                                 const int* __restrict__ dst, int E,
                                                 int* __restrict__ cursor,
                                                 int* __restrict__ srcSorted) {
    int e = blockIdx.x * 256 + threadIdx.x;
    if (e < E) {
        int pos = atomicAdd(&cursor[dst[e]], 1);
        srcSorted[pos] = src[e];
    }
}

// ---------------- gather-mean over bf16 features ----------------
__global__ __launch_bounds__(256) void gather_mean_k(const u16* __restrict__ feat,
                                                     const int* __restrict__ rowptr,
                                                     const int* __restrict__ srcIdx,
                                                     int nDst, int nPad,
                                                     u16* __restrict__ outAgg) {
    int r = blockIdx.x * 4 + (threadIdx.x >> 6);
    if (r >= nPad) return;
    int lane = threadIdx.x & 63;
    float ax = 0.f, ay = 0.f, az = 0.f, aw = 0.f;
    int deg = 0;
    if (r < nDst) {
        int e0 = rowptr[r], e1 = rowptr[r + 1];
        deg = e1 - e0;
        int e = e0;
        for (; e + 1 < e1; e += 2) {
            int s0 = srcIdx[e], s1 = srcIdx[e + 1];
            ushort4 v0 = *reinterpret_cast<const ushort4*>(feat + (size_t)s0 * H + lane * 4);
            ushort4 v1 = *reinterpret_cast<const ushort4*>(feat + (size_t)s1 * H + lane * 4);
            ax += bf2f(v0.x) + bf2f(v1.x);
            ay += bf2f(v0.y) + bf2f(v1.y);
            az += bf2f(v0.z) + bf2f(v1.z);
            aw += bf2f(v0.w) + bf2f(v1.w);
        }
        if (e < e1) {
            int s0 = srcIdx[e];
            ushort4 v0 = *reinterpret_cast<const ushort4*>(feat + (size_t)s0 * H + lane * 4);
            ax += bf2f(v0.x); ay += bf2f(v0.y); az += bf2f(v0.z); aw += bf2f(v0.w);
        }
    }
    float inv = deg > 0 ? 1.f / (float)deg : 0.f;
    ushort4 o;
    o.x = f2bf(ax * inv); o.y = f2bf(ay * inv); o.z = f2bf(az * inv); o.w = f2bf(aw * inv);
    *reinterpret_cast<ushort4*>(outAgg + (size_t)r * H + lane * 4) = o;
}

// ---------------- bf16 MFMA GEMM, 2-phase pipelined ----------------
// out[128 x 256 tile] = sum_p A_p @ Wt_p^T (+bias)(+relu+res)
// A_p: [Mpad][K] bf16. Wt_p: [256][K] bf16. All pairs share K.
// 512 threads = 8 waves (2x4); wave tile 64x64; BK=32.
// LDS per phase: A 128x32 (8KB) + B 256x32 (16KB); XOR-swizzle u^=(row>>1)&3.
struct GemmArgs {
    const u16* A[4];
    const u16* Wt[4];
    int K;       // uniform across pairs
    int nPairs;
    const float* bias1;  // nullable
    const float* bias2;  // nullable
    const u16* res;      // bf16 residual (mode 1)
    void* out;           // u16 (mode 0/1) or float (mode 2)
    int mode;
};

__global__ __launch_bounds__(512, 4) void gemm_bf16_k(GemmArgs g) {
    __shared__ char lds[2][24576];  // [phase][A:0..8191 | B:8192..24575]
    const int tid = threadIdx.x;
    const int lane = tid & 63;
    const int wid = tid >> 6;
    const int wm = wid >> 2;
    const int wn = wid & 3;
    const int row0 = blockIdx.x * 128;
    const int K = g.K;

    // ---- staging source offsets (bf16 elements), inverse-swizzled (rule #21) ----
    const int srow = tid >> 2;                       // 0..127
    const int au = (tid & 3) ^ ((srow >> 1) & 3);
    const int ofsA = (row0 + srow) * K + au * 8;
    const int ofsB1 = srow * K + au * 8;             // B rows 0..127 (same swizzle fn)
    const int brow2 = 128 + srow;
    const int bu2 = (tid & 3) ^ ((brow2 >> 1) & 3);
    const int ofsB2 = brow2 * K + bu2 * 8;

    // ---- reader LDS byte offsets (swizzled) ----
    int a_off[4], b_off[4];
#pragma unroll
    for (int mi = 0; mi < 4; ++mi) {
        int row = wm * 64 + mi * 16 + (lane & 15);
        int u = (lane >> 4) ^ ((row >> 1) & 3);
        a_off[mi] = row * 64 + u * 16;
    }
#pragma unroll
    for (int ni = 0; ni < 4; ++ni) {
        int row = wn * 64 + ni * 16 + (lane & 15);
        int u = (lane >> 4) ^ ((row >> 1) & 3);
        b_off[ni] = 8192 + row * 64 + u * 16;
    }

#define STAGE(p_, kk_, ph_)                                                                       \
    do {                                                                                          \
        const u16* A_ = g.A[p_];                                                                  \
        const u16* W_ = g.Wt[p_];                                                                 \
        __builtin_amdgcn_global_load_lds(                                                         \
            (const __attribute__((address_space(1))) void*)(A_ + ofsA + (kk_)),                   \
            (__attribute__((address_space(3))) void*)(lds[ph_] + wid * 1024), 16, 0, 0);          \
        __builtin_amdgcn_global_load_lds(                                                         \
            (const __attribute__((address_space(1))) void*)(W_ + ofsB1 + (kk_)),                  \
            (__attribute__((address_space(3))) void*)(lds[ph_] + 8192 + wid * 1024), 16, 0, 0);   \
        __builtin_amdgcn_global_load_lds(                                                         \
            (const __attribute__((address_space(1))) void*)(W_ + ofsB2 + (kk_)),                  \
            (__attribute__((address_space(3))) void*)(lds[ph_] + 16384 + wid * 1024), 16, 0, 0);  \
    } while (0)

    f32x4 acc[4][4] = {};
    const int T = g.nPairs * (K >> 5);

    STAGE(0, 0, 0);
    int pn = 0, kn = 32;
    if (kn == K) { kn = 0; pn = 1; }

    for (int s = 0; s < T; ++s) {
        const int ph = s & 1;
        if (s + 1 < T) {
            STAGE(pn, kn, ph ^ 1);
            kn += 32;
            if (kn == K) { kn = 0; ++pn; }
            asm volatile("s_waitcnt vmcnt(3)" ::: "memory");  // stage(s) landed; stage(s+1) in flight
        } else {
            asm volatile("s_waitcnt vmcnt(0)" ::: "memory");
        }
        __builtin_amdgcn_sched_barrier(0);
        __builtin_amdgcn_s_barrier();  // all waves' stage(s) visible

        bf16x8 af[4], bf[4];
#pragma unroll
        for (int mi = 0; mi < 4; ++mi)
            af[mi] = *reinterpret_cast<const bf16x8*>(lds[ph] + a_off[mi]);
#pragma unroll
        for (int ni = 0; ni < 4; ++ni)
            bf[ni] = *reinterpret_cast<const bf16x8*>(lds[ph] + b_off[ni]);
#pragma unroll
        for (int mi = 0; mi < 4; ++mi)
#pragma unroll
            for (int ni = 0; ni < 4; ++ni)
                acc[mi][ni] = __builtin_amdgcn_mfma_f32_16x16x32_bf16(af[mi], bf[ni],
                                                                      acc[mi][ni], 0, 0, 0);
        __builtin_amdgcn_sched_barrier(0);
        __builtin_amdgcn_s_barrier();  // reads of lds[ph] done -> next stage may overwrite
    }
#undef STAGE

    // ---- epilogue: D mapping col = lane&15, row = (lane>>4)*4 + j ----
    const int ccol = wn * 64 + (lane & 15);
    const int crow0 = row0 + wm * 64 + ((lane >> 4) << 2);
#pragma unroll
    for (int ni = 0; ni < 4; ++ni) {
        int c = ccol + ni * 16;
        float bv = 0.f;
        if (g.bias1) bv += g.bias1[c];
        if (g.bias2) bv += g.bias2[c];
#pragma unroll
        for (int mi = 0; mi < 4; ++mi) {
#pragma unroll
            for (int j = 0; j < 4; ++j) {
                int r = crow0 + mi * 16 + j;
                size_t idx = (size_t)r * H + c;
                float v = acc[mi][ni][j] + bv;
                if (g.mode == 1) {
                    v = fmaxf(v, 0.f) + bf2f(g.res[idx]);
                    ((u16*)g.out)[idx] = f2bf(v);
                } else if (g.mode == 0) {
                    ((u16*)g.out)[idx] = f2bf(v);
                } else {
                    ((float*)g.out)[idx] = v;
                }
            }
        }
    }
}

// ---------------- row L2 normalize: padded fp32 src -> d_out ----------------
__global__ __launch_bounds__(256) void l2norm_k(const float* __restrict__ srcE,
                                                const float* __restrict__ srcC,
                                                float* __restrict__ out) {
    int row = blockIdx.x;
    const float* src = (row < N_E) ? (srcE + (size_t)row * H)
                                   : (srcC + (size_t)(row - N_E) * H);
    float v = src[threadIdx.x];
    float s = v * v;
#pragma unroll
    for (int o = 32; o > 0; o >>= 1) s += __shfl_down(s, o);
    __shared__ float partial[4];
    if ((threadIdx.x & 63) == 0) partial[threadIdx.x >> 6] = s;
    __syncthreads();
    float tot = partial[0] + partial[1] + partial[2] + partial[3];
    float n = sqrtf(tot);
    out[(size_t)row * H + threadIdx.x] = v / fmaxf(n, 1e-12f);
}

extern "C" void kernel_launch(void* const* d_in, const int* in_sizes, int n_in,
                              void* d_out, int out_size, void* d_ws, size_t ws_size,
                              hipStream_t stream) {
    const float* x_e = (const float*)d_in[0];
    const float* x_c = (const float*)d_in[1];
    const int* e_ee = (const int*)d_in[2];
    const int* e_ec = (const int*)d_in[3];
    const int* e_ce = (const int*)d_in[4];
    const float* P_e = (const float*)d_in[5];
    const float* P_c = (const float*)d_in[6];
    const float* Wl1 = (const float*)d_in[7];
    const float* bl1 = (const float*)d_in[8];
    const float* Wr1 = (const float*)d_in[9];
    const float* Wl2 = (const float*)d_in[10];
    const float* bl2 = (const float*)d_in[11];
    const float* Wr2 = (const float*)d_in[12];
    float* out = (float*)d_out;

    const size_t EHp = (size_t)ME_PAD * H;
    const size_t CHp = (size_t)MC_PAD * H;

    u16* us = (u16*)d_ws;
    u16* x_eb = us;  us += (size_t)ME_PAD * D_E;
    u16* x_cb = us;  us += (size_t)MC_PAD * D_C;
    u16* he0 = us;   us += EHp;
    u16* he1 = us;   us += EHp;
    u16* aggE1 = us; us += EHp;
    u16* aggE2 = us; us += EHp;
    u16* hc0 = us;   us += CHp;
    u16* hc1 = us;   us += CHp;
    u16* aggC = us;  us += CHp;
    u16* PeT = us;   us += H * D_E;
    u16* PcT = us;   us += H * D_C;
    u16* WlT1 = us;  us += 3 * H * H;
    u16* WrT1 = us;  us += 3 * H * H;
    u16* WlT2 = us;  us += 3 * H * H;
    u16* WrT2 = us;  us += 3 * H * H;
    // fp32 conv2 outputs overlay the (then-dead) x_eb / x_cb regions
    float* opadE = (float*)x_eb;
    float* opadC = (float*)x_cb;

    int* ip = (int*)us;
    int* eePtr = ip;  ip += N_E + 1;
    int* eeSrc = ip;  ip += E_EE;
    int* eeCur = ip;  ip += N_E;
    int* cePtr = ip;  ip += N_E + 1;
    int* ceSrc = ip;  ip += E_CE;
    int* ceCur = ip;  ip += N_E;
    int* ecPtr = ip;  ip += N_C + 1;
    int* ecSrc = ip;  ip += E_EC;
    int* ecCur = ip;  ip += N_C;
    int* cntAll = ip; ip += SCAN_N;
    int* part = ip;   ip += SCAN_N;
    int* bsum = ip;   ip += SCAN_NB + 1;

    const int WHH = H * H;

    // --- CSR build (combined histogram + hierarchical scan) ---
    hipMemsetAsync(cntAll, 0, (size_t)SCAN_N * sizeof(int), stream);
    hist_k<<<(E_EE + 255) / 256, 256, 0, stream>>>(e_ee + E_EE, E_EE, cntAll);
    hist_k<<<(E_CE + 255) / 256, 256, 0, stream>>>(e_ce + E_CE, E_CE, cntAll + N_E);
    hist_k<<<(E_EC + 255) / 256, 256, 0, stream>>>(e_ec + E_EC, E_EC, cntAll + 2 * N_E);
    scan_blk_k<<<SCAN_NB, 1024, 0, stream>>>(cntAll, part, bsum);
    scan_top_k<<<1, 1024, 0, stream>>>(bsum);
    scan_out_k<<<SCAN_NB, 1024, 0, stream>>>(part, bsum, eePtr, eeCur, cePtr, ceCur, ecPtr, ecCur);
    reorder_k<<<(E_EE + 255) / 256, 256, 0, stream>>>(e_ee, e_ee + E_EE, E_EE, eeCur, eeSrc);
    reorder_k<<<(E_CE + 255) / 256, 256, 0, stream>>>(e_ce, e_ce + E_CE, E_CE, ceCur, ceSrc);
    reorder_k<<<(E_EC + 255) / 256, 256, 0, stream>>>(e_ec, e_ec + E_EC, E_EC, ecCur, ecSrc);

    // --- bf16 conversions ---
    cvt_pad_k<<<ME_PAD, 256, 0, stream>>>(x_e, x_eb, N_E, D_E);
    cvt_pad_k<<<MC_PAD, 256, 0, stream>>>(x_c, x_cb, N_C, D_C);
    {
        dim3 blk(32, 32);
        transpose_w_k<<<dim3(D_E / 32, H / 32), blk, 0, stream>>>(P_e, PeT, D_E);
        transpose_w_k<<<dim3(D_C / 32, H / 32), blk, 0, stream>>>(P_c, PcT, D_C);
        for (int p = 0; p < 3; ++p) {
            transpose_w_k<<<dim3(H / 32, H / 32), blk, 0, stream>>>(Wl1 + p * WHH, WlT1 + p * WHH, H);
            transpose_w_k<<<dim3(H / 32, H / 32), blk, 0, stream>>>(Wr1 + p * WHH, WrT1 + p * WHH, H);
            transpose_w_k<<<dim3(H / 32, H / 32), blk, 0, stream>>>(Wl2 + p * WHH, WlT2 + p * WHH, H);
            transpose_w_k<<<dim3(H / 32, H / 32), blk, 0, stream>>>(Wr2 + p * WHH, WrT2 + p * WHH, H);
        }
    }

    const int gridE = ME_PAD / 128, gridC = MC_PAD / 128;

    // --- projections ---
    {
        GemmArgs g{};
        g.A[0] = x_eb; g.Wt[0] = PeT; g.K = D_E; g.nPairs = 1;
        g.out = he0; g.mode = 0;
        gemm_bf16_k<<<gridE, 512, 0, stream>>>(g);
    }
    {
        GemmArgs g{};
        g.A[0] = x_cb; g.Wt[0] = PcT; g.K = D_C; g.nPairs = 1;
        g.out = hc0; g.mode = 0;
        gemm_bf16_k<<<gridC, 512, 0, stream>>>(g);
    }

    // --- conv1 ---
    gather_mean_k<<<ME_PAD / 4, 256, 0, stream>>>(he0, eePtr, eeSrc, N_E, ME_PAD, aggE1);
    gather_mean_k<<<ME_PAD / 4, 256, 0, stream>>>(hc0, cePtr, ceSrc, N_E, ME_PAD, aggE2);
    gather_mean_k<<<MC_PAD / 4, 256, 0, stream>>>(he0, ecPtr, ecSrc, N_C, MC_PAD, aggC);
    {
        GemmArgs g{};
        g.A[0] = aggE1; g.Wt[0] = WlT1 + 0 * WHH;
        g.A[1] = aggE2; g.Wt[1] = WlT1 + 2 * WHH;
        g.A[2] = he0;   g.Wt[2] = WrT1 + 0 * WHH;
        g.A[3] = he0;   g.Wt[3] = WrT1 + 2 * WHH;
        g.K = H; g.nPairs = 4;
        g.bias1 = bl1 + 0 * H; g.bias2 = bl1 + 2 * H;
        g.res = he0; g.out = he1; g.mode = 1;
        gemm_bf16_k<<<gridE, 512, 0, stream>>>(g);
    }
    {
        GemmArgs g{};
        g.A[0] = aggC; g.Wt[0] = WlT1 + 1 * WHH;
        g.A[1] = hc0;  g.Wt[1] = WrT1 + 1 * WHH;
        g.K = H; g.nPairs = 2;
        g.bias1 = bl1 + 1 * H;
        g.res = hc0; g.out = hc1; g.mode = 1;
        gemm_bf16_k<<<gridC, 512, 0, stream>>>(g);
    }

    // --- conv2 ---
    gather_mean_k<<<ME_PAD / 4, 256, 0, stream>>>(he1, eePtr, eeSrc, N_E, ME_PAD, aggE1);
    gather_mean_k<<<ME_PAD / 4, 256, 0, stream>>>(hc1, cePtr, ceSrc, N_E, ME_PAD, aggE2);
    gather_mean_k<<<MC_PAD / 4, 256, 0, stream>>>(he1, ecPtr, ecSrc, N_C, MC_PAD, aggC);
    {
        GemmArgs g{};
        g.A[0] = aggE1; g.Wt[0] = WlT2 + 0 * WHH;
        g.A[1] = aggE2; g.Wt[1] = WlT2 + 2 * WHH;
        g.A[2] = he1;   g.Wt[2] = WrT2 + 0 * WHH;
        g.A[3] = he1;   g.Wt[3] = WrT2 + 2 * WHH;
        g.K = H; g.nPairs = 4;
        g.bias1 = bl2 + 0 * H; g.bias2 = bl2 + 2 * H;
        g.out = opadE; g.mode = 2;
        gemm_bf16_k<<<gridE, 512, 0, stream>>>(g);
    }
    {
        GemmArgs g{};
        g.A[0] = aggC; g.Wt[0] = WlT2 + 1 * WHH;
        g.A[1] = hc1;  g.Wt[1] = WrT2 + 1 * WHH;
        g.K = H; g.nPairs = 2;
        g.bias1 = bl2 + 1 * H;
        g.out = opadC; g.mode = 2;
        gemm_bf16_k<<<gridC, 512, 0, stream>>>(g);
    }

    // --- final row-wise L2 normalize -> d_out ---
    l2norm_k<<<N_E + N_C, 256, 0, stream>>>(opadE, opadC, out);
}

// Round 5
// 982.365 us; speedup vs baseline: 14.2182x; 1.2310x over previous
//
#include <hip/hip_runtime.h>
#include <hip/hip_bf16.h>

#define N_E 100000
#define N_C 50000
#define H 256
#define D_E 768
#define D_C 1024
#define E_EE 800000
#define E_EC 400000
#define E_CE 400000

#define ME_PAD 100096  // 782*128
#define MC_PAD 50048   // 391*128

typedef unsigned short u16;
typedef __attribute__((ext_vector_type(8))) short bf16x8;
typedef __attribute__((ext_vector_type(4))) float f32x4;

__device__ __forceinline__ float bf2f(u16 x) {
    unsigned u = ((unsigned)x) << 16;
    return __builtin_bit_cast(float, u);
}
__device__ __forceinline__ u16 f2bf(float f) {
    unsigned u = __builtin_bit_cast(unsigned, f);
    u = (u + 0x7fffu + ((u >> 16) & 1u)) >> 16;
    return (u16)u;
}

// ---------------- weight transpose: in [K][256] fp32 -> out [256][K] bf16 ----------------
__global__ __launch_bounds__(1024) void transpose_w_k(const float* __restrict__ in,
                                                      u16* __restrict__ out, int K) {
    __shared__ float t[32][33];
    int k0 = blockIdx.x * 32, n0 = blockIdx.y * 32;
    int tx = threadIdx.x, ty = threadIdx.y;
    t[ty][tx] = in[(size_t)(k0 + ty) * H + n0 + tx];
    __syncthreads();
    out[(size_t)(n0 + ty) * K + k0 + tx] = f2bf(t[tx][ty]);
}

// transpose of (a + b), K = H (for folded Wr entity weights)
__global__ __launch_bounds__(1024) void transpose_wsum_k(const float* __restrict__ a,
                                                         const float* __restrict__ b,
                                                         u16* __restrict__ out) {
    __shared__ float t[32][33];
    int k0 = blockIdx.x * 32, n0 = blockIdx.y * 32;
    int tx = threadIdx.x, ty = threadIdx.y;
    size_t idx = (size_t)(k0 + ty) * H + n0 + tx;
    t[ty][tx] = a[idx] + b[idx];
    __syncthreads();
    out[(size_t)(n0 + ty) * H + k0 + tx] = f2bf(t[tx][ty]);
}

// ---------------- CSR build: combined histogram + hierarchical scan ----------------
__global__ __launch_bounds__(256) void hist_k(const int* __restrict__ dst, int E,
                                              int* __restrict__ cnt) {
    int i = blockIdx.x * 256 + threadIdx.x;
    if (i < E) atomicAdd(&cnt[dst[i]], 1);
}

#define SCAN_N (2 * N_E + N_C)  // 250000
#define SCAN_NB ((SCAN_N + 1023) / 1024)

__global__ __launch_bounds__(1024) void scan_blk_k(const int* __restrict__ cnt,
                                                   int* __restrict__ part,
                                                   int* __restrict__ bsum) {
    __shared__ int sm[1024];
    int i = blockIdx.x * 1024 + threadIdx.x;
    int v = (i < SCAN_N) ? cnt[i] : 0;
    sm[threadIdx.x] = v;
    __syncthreads();
    for (int off = 1; off < 1024; off <<= 1) {
        int t = (threadIdx.x >= off) ? sm[threadIdx.x - off] : 0;
        __syncthreads();
        sm[threadIdx.x] += t;
        __syncthreads();
    }
    if (i < SCAN_N) part[i] = sm[threadIdx.x] - v;
    if (threadIdx.x == 1023) bsum[blockIdx.x] = sm[1023];
}

__global__ __launch_bounds__(1024) void scan_top_k(int* __restrict__ bsum) {
    __shared__ int sm[1024];
    int v = (threadIdx.x < SCAN_NB) ? bsum[threadIdx.x] : 0;
    sm[threadIdx.x] = v;
    __syncthreads();
    for (int off = 1; off < 1024; off <<= 1) {
        int t = (threadIdx.x >= off) ? sm[threadIdx.x - off] : 0;
        __syncthreads();
        sm[threadIdx.x] += t;
        __syncthreads();
    }
    if (threadIdx.x < SCAN_NB) bsum[threadIdx.x] = sm[threadIdx.x] - v;
}

__global__ __launch_bounds__(1024) void scan_out_k(const int* __restrict__ part,
                                                   const int* __restrict__ bsum,
                                                   int* __restrict__ eePtr, int* __restrict__ eeCur,
                                                   int* __restrict__ cePtr, int* __restrict__ ceCur,
                                                   int* __restrict__ ecPtr, int* __restrict__ ecCur) {
    int i = blockIdx.x * 1024 + threadIdx.x;
    if (i < SCAN_N) {
        int v = part[i] + bsum[blockIdx.x];
        if (i < N_E) {
            eePtr[i] = v; eeCur[i] = v;
        } else if (i < 2 * N_E) {
            int j = i - N_E, w = v - E_EE;
            cePtr[j] = w; ceCur[j] = w;
        } else {
            int j = i - 2 * N_E, w = v - (E_EE + E_CE);
            ecPtr[j] = w; ecCur[j] = w;
        }
    }
    if (i == 0) {
        eePtr[N_E] = E_EE;
        cePtr[N_E] = E_CE;
        ecPtr[N_C] = E_EC;
    }
}

__global__ __launch_bounds__(256) void reorder_k(const int* __restrict__ src,
                                                 const int* __restrict__ dst, int E,
                                                 int* __restrict__ cursor,
                                                 int* __restrict__ srcSorted) {
    int e = blockIdx.x * 256 + threadIdx.x;
    if (e < E) {
        int pos = atomicAdd(&cursor[dst[e]], 1);
        srcSorted[pos] = src[e];
    }
}

// ---------------- gather-mean over bf16 features ----------------
__global__ __launch_bounds__(256) void gather_mean_k(const u16* __restrict__ feat,
                                                     const int* __restrict__ rowptr,
                                                     const int* __restrict__ srcIdx,
                                                     int nDst, int nPad,
                                                     u16* __restrict__ outAgg) {
    int r = blockIdx.x * 4 + (threadIdx.x >> 6);
    if (r >= nPad) return;
    int lane = threadIdx.x & 63;
    float ax = 0.f, ay = 0.f, az = 0.f, aw = 0.f;
    int deg = 0;
    if (r < nDst) {
        int e0 = rowptr[r], e1 = rowptr[r + 1];
        deg = e1 - e0;
        int e = e0;
        for (; e + 1 < e1; e += 2) {
            int s0 = srcIdx[e], s1 = srcIdx[e + 1];
            ushort4 v0 = *reinterpret_cast<const ushort4*>(feat + (size_t)s0 * H + lane * 4);
            ushort4 v1 = *reinterpret_cast<const ushort4*>(feat + (size_t)s1 * H + lane * 4);
            ax += bf2f(v0.x) + bf2f(v1.x);
            ay += bf2f(v0.y) + bf2f(v1.y);
            az += bf2f(v0.z) + bf2f(v1.z);
            aw += bf2f(v0.w) + bf2f(v1.w);
        }
        if (e < e1) {
            int s0 = srcIdx[e];
            ushort4 v0 = *reinterpret_cast<const ushort4*>(feat + (size_t)s0 * H + lane * 4);
            ax += bf2f(v0.x); ay += bf2f(v0.y); az += bf2f(v0.z); aw += bf2f(v0.w);
        }
    }
    float inv = deg > 0 ? 1.f / (float)deg : 0.f;
    ushort4 o;
    o.x = f2bf(ax * inv); o.y = f2bf(ay * inv); o.z = f2bf(az * inv); o.w = f2bf(aw * inv);
    *reinterpret_cast<ushort4*>(outAgg + (size_t)r * H + lane * 4) = o;
}

// ================= bf16 MFMA GEMM (2-phase pipelined) =================
// tile 128 x 256, 8 waves (2x4), wave tile 64x64, BK=32.
// LDS phase: A 128x32 @0 (8KB) | B 256x32 @8192 (16KB); swizzle u ^= (row>>1)&3.

struct GemmArgs {
    const u16* A[3];
    const u16* Wt[3];
    int K;       // uniform across pairs
    int nPairs;
    const float* bias1;  // nullable
    const float* bias2;  // nullable
    const u16* res;      // bf16 residual (mode 1)
    void* out;           // u16 (mode 1) or float (mode 2)
    int Mvalid;          // mode 2: real row count for store guard
    int mode;            // 1 = relu(acc+b)+res -> bf16 ; 2 = l2norm(acc+b) -> fp32
};

__global__ __launch_bounds__(512, 4) void gemm_bf16_k(GemmArgs g) {
    __shared__ char lds[2][24576];
    __shared__ float rowsq[128];
    const int tid = threadIdx.x;
    const int lane = tid & 63;
    const int wid = tid >> 6;
    const int wm = wid >> 2;
    const int wn = wid & 3;
    const int row0 = blockIdx.x * 128;
    const int K = g.K;

    // staging source offsets (inverse-swizzled; linear LDS dest per rule #21)
    const int srow = tid >> 2;
    const int au = (tid & 3) ^ ((srow >> 1) & 3);
    const int ofsA = (row0 + srow) * K + au * 8;
    const int ofsB1 = srow * K + au * 8;
    const int brow2 = 128 + srow;
    const int bu2 = (tid & 3) ^ ((brow2 >> 1) & 3);
    const int ofsB2 = brow2 * K + bu2 * 8;

    // reader LDS byte offsets (swizzled)
    int a_off[4], b_off[4];
#pragma unroll
    for (int mi = 0; mi < 4; ++mi) {
        int row = wm * 64 + mi * 16 + (lane & 15);
        int u = (lane >> 4) ^ ((row >> 1) & 3);
        a_off[mi] = row * 64 + u * 16;
    }
#pragma unroll
    for (int ni = 0; ni < 4; ++ni) {
        int row = wn * 64 + ni * 16 + (lane & 15);
        int u = (lane >> 4) ^ ((row >> 1) & 3);
        b_off[ni] = 8192 + row * 64 + u * 16;
    }

#define STAGE(p_, kk_, ph_)                                                                       \
    do {                                                                                          \
        const u16* A_ = g.A[p_];                                                                  \
        const u16* W_ = g.Wt[p_];                                                                 \
        __builtin_amdgcn_global_load_lds(                                                         \
            (const __attribute__((address_space(1))) void*)(A_ + ofsA + (kk_)),                   \
            (__attribute__((address_space(3))) void*)(lds[ph_] + wid * 1024), 16, 0, 0);          \
        __builtin_amdgcn_global_load_lds(                                                         \
            (const __attribute__((address_space(1))) void*)(W_ + ofsB1 + (kk_)),                  \
            (__attribute__((address_space(3))) void*)(lds[ph_] + 8192 + wid * 1024), 16, 0, 0);   \
        __builtin_amdgcn_global_load_lds(                                                         \
            (const __attribute__((address_space(1))) void*)(W_ + ofsB2 + (kk_)),                  \
            (__attribute__((address_space(3))) void*)(lds[ph_] + 16384 + wid * 1024), 16, 0, 0);  \
    } while (0)

    f32x4 acc[4][4] = {};
    const int T = g.nPairs * (K >> 5);

    STAGE(0, 0, 0);
    int pn = 0, kn = 32;
    if (kn == K) { kn = 0; pn = 1; }

    for (int s = 0; s < T; ++s) {
        const int ph = s & 1;
        if (s + 1 < T) {
            STAGE(pn, kn, ph ^ 1);
            kn += 32;
            if (kn == K) { kn = 0; ++pn; }
            asm volatile("s_waitcnt vmcnt(3)" ::: "memory");
        } else {
            asm volatile("s_waitcnt vmcnt(0)" ::: "memory");
        }
        __builtin_amdgcn_sched_barrier(0);
        __builtin_amdgcn_s_barrier();

        bf16x8 af[4], bfr[4];
#pragma unroll
        for (int mi = 0; mi < 4; ++mi)
            af[mi] = *reinterpret_cast<const bf16x8*>(lds[ph] + a_off[mi]);
#pragma unroll
        for (int ni = 0; ni < 4; ++ni)
            bfr[ni] = *reinterpret_cast<const bf16x8*>(lds[ph] + b_off[ni]);
#pragma unroll
        for (int mi = 0; mi < 4; ++mi)
#pragma unroll
            for (int ni = 0; ni < 4; ++ni)
                acc[mi][ni] = __builtin_amdgcn_mfma_f32_16x16x32_bf16(af[mi], bfr[ni],
                                                                      acc[mi][ni], 0, 0, 0);
        __builtin_amdgcn_sched_barrier(0);
        __builtin_amdgcn_s_barrier();
    }
#undef STAGE

    // ---- epilogue: D mapping col = lane&15, row = (lane>>4)*4 + j ----
    const int ccol = wn * 64 + (lane & 15);
    const int crow0 = row0 + wm * 64 + ((lane >> 4) << 2);
    float bv[4];
#pragma unroll
    for (int ni = 0; ni < 4; ++ni) {
        int c = ccol + ni * 16;
        float b = 0.f;
        if (g.bias1) b += g.bias1[c];
        if (g.bias2) b += g.bias2[c];
        bv[ni] = b;
    }

    if (g.mode == 1) {
#pragma unroll
        for (int ni = 0; ni < 4; ++ni) {
            int c = ccol + ni * 16;
#pragma unroll
            for (int mi = 0; mi < 4; ++mi) {
#pragma unroll
                for (int j = 0; j < 4; ++j) {
                    int r = crow0 + mi * 16 + j;
                    size_t idx = (size_t)r * H + c;
                    float v = fmaxf(acc[mi][ni][j] + bv[ni], 0.f) + bf2f(g.res[idx]);
                    ((u16*)g.out)[idx] = f2bf(v);
                }
            }
        }
    } else {
        // fused row L2-norm: block covers full rows (BN == H == 256)
        if (tid < 128) rowsq[tid] = 0.f;
        __syncthreads();
#pragma unroll
        for (int mi = 0; mi < 4; ++mi) {
#pragma unroll
            for (int j = 0; j < 4; ++j) {
                float p = 0.f;
#pragma unroll
                for (int ni = 0; ni < 4; ++ni) {
                    float v = acc[mi][ni][j] + bv[ni];
                    p += v * v;
                }
                p += __shfl_xor(p, 1);
                p += __shfl_xor(p, 2);
                p += __shfl_xor(p, 4);
                p += __shfl_xor(p, 8);
                if ((lane & 15) == 0) {
                    int rl = wm * 64 + mi * 16 + ((lane >> 4) << 2) + j;
                    atomicAdd(&rowsq[rl], p);
                }
            }
        }
        __syncthreads();
#pragma unroll
        for (int mi = 0; mi < 4; ++mi) {
#pragma unroll
            for (int j = 0; j < 4; ++j) {
                int rl = wm * 64 + mi * 16 + ((lane >> 4) << 2) + j;
                int r = row0 + rl;
                if (r < g.Mvalid) {
                    float inv = 1.f / fmaxf(sqrtf(rowsq[rl]), 1e-12f);
#pragma unroll
                    for (int ni = 0; ni < 4; ++ni) {
                        int c = ccol + ni * 16;
                        float v = acc[mi][ni][j] + bv[ni];
                        ((float*)g.out)[(size_t)r * H + c] = v * inv;
                    }
                }
            }
        }
    }
}

// ================= projection GEMM: fp32 A (in-kernel bf16 cvt), bf16 Wt =================
struct ProjArgs {
    const float* A;  // [M][K] fp32, unpadded (rows clamped)
    const u16* Wt;   // [256][K] bf16
    int K;
    int M;           // real row count
    u16* out;        // [Mpad][256] bf16 (all tile rows stored)
};

__global__ __launch_bounds__(512, 4) void gemm_proj_k(ProjArgs g) {
    __shared__ char lds[2][24576];
    const int tid = threadIdx.x;
    const int lane = tid & 63;
    const int wid = tid >> 6;
    const int wm = wid >> 2;
    const int wn = wid & 3;
    const int row0 = blockIdx.x * 128;
    const int K = g.K;

    // A reg-staging: thread covers (srow, 8-k unit cunit); clamp row (no pad buffer)
    const int srow = tid >> 2;
    const int cunit = tid & 3;
    const int aRow = min(row0 + srow, g.M - 1);
    const float* pA = g.A + (size_t)aRow * K + cunit * 8;
    const int aDst = srow * 64 + (cunit ^ ((srow >> 1) & 3)) * 16;  // swizzled LDS byte off

    // B staging via global_load_lds (inverse-swizzled source)
    const int bu1 = cunit ^ ((srow >> 1) & 3);
    const int ofsB1 = srow * K + bu1 * 8;
    const int brow2 = 128 + srow;
    const int bu2 = cunit ^ ((brow2 >> 1) & 3);
    const int ofsB2 = brow2 * K + bu2 * 8;

    int a_off[4], b_off[4];
#pragma unroll
    for (int mi = 0; mi < 4; ++mi) {
        int row = wm * 64 + mi * 16 + (lane & 15);
        int u = (lane >> 4) ^ ((row >> 1) & 3);
        a_off[mi] = row * 64 + u * 16;
    }
#pragma unroll
    for (int ni = 0; ni < 4; ++ni) {
        int row = wn * 64 + ni * 16 + (lane & 15);
        int u = (lane >> 4) ^ ((row >> 1) & 3);
        b_off[ni] = 8192 + row * 64 + u * 16;
    }

#define BSTAGE(kk_, ph_)                                                                          \
    do {                                                                                          \
        __builtin_amdgcn_global_load_lds(                                                         \
            (const __attribute__((address_space(1))) void*)(g.Wt + ofsB1 + (kk_)),               \
            (__attribute__((address_space(3))) void*)(lds[ph_] + 8192 + wid * 1024), 16, 0, 0);   \
        __builtin_amdgcn_global_load_lds(                                                         \
            (const __attribute__((address_space(1))) void*)(g.Wt + ofsB2 + (kk_)),               \
            (__attribute__((address_space(3))) void*)(lds[ph_] + 16384 + wid * 1024), 16, 0, 0);  \
    } while (0)

    f32x4 acc[4][4] = {};
    const int T = K >> 5;

    BSTAGE(0, 0);
    float4 c0 = *reinterpret_cast<const float4*>(pA);
    float4 c1 = *reinterpret_cast<const float4*>(pA + 4);

    for (int s = 0; s < T; ++s) {
        const int ph = s & 1;
        float4 n0 = make_float4(0.f, 0.f, 0.f, 0.f), n1 = n0;
        if (s + 1 < T) {
            BSTAGE((s + 1) * 32, ph ^ 1);
            n0 = *reinterpret_cast<const float4*>(pA + (s + 1) * 32);
            n1 = *reinterpret_cast<const float4*>(pA + (s + 1) * 32 + 4);
        }
        // convert + write current A sub-tile (compiler inserts vmcnt for c0/c1;
        // FIFO => B(s) gload_lds also complete)
        union { bf16x8 v; u16 e[8]; } pk;
        pk.e[0] = f2bf(c0.x); pk.e[1] = f2bf(c0.y); pk.e[2] = f2bf(c0.z); pk.e[3] = f2bf(c0.w);
        pk.e[4] = f2bf(c1.x); pk.e[5] = f2bf(c1.y); pk.e[6] = f2bf(c1.z); pk.e[7] = f2bf(c1.w);
        *reinterpret_cast<bf16x8*>(lds[ph] + aDst) = pk.v;
        asm volatile("s_waitcnt lgkmcnt(0)" ::: "memory");
        __builtin_amdgcn_sched_barrier(0);
        __builtin_amdgcn_s_barrier();

        bf16x8 af[4], bfr[4];
#pragma unroll
        for (int mi = 0; mi < 4; ++mi)
            af[mi] = *reinterpret_cast<const bf16x8*>(lds[ph] + a_off[mi]);
#pragma unroll
        for (int ni = 0; ni < 4; ++ni)
            bfr[ni] = *reinterpret_cast<const bf16x8*>(lds[ph] + b_off[ni]);
#pragma unroll
        for (int mi = 0; mi < 4; ++mi)
#pragma unroll
            for (int ni = 0; ni < 4; ++ni)
                acc[mi][ni] = __builtin_amdgcn_mfma_f32_16x16x32_bf16(af[mi], bfr[ni],
                                                                      acc[mi][ni], 0, 0, 0);
        __builtin_amdgcn_sched_barrier(0);
        __builtin_amdgcn_s_barrier();
        c0 = n0; c1 = n1;
    }
#undef BSTAGE

    const int ccol = wn * 64 + (lane & 15);
    const int crow0 = row0 + wm * 64 + ((lane >> 4) << 2);
#pragma unroll
    for (int ni = 0; ni < 4; ++ni) {
        int c = ccol + ni * 16;
#pragma unroll
        for (int mi = 0; mi < 4; ++mi) {
#pragma unroll
            for (int j = 0; j < 4; ++j) {
                int r = crow0 + mi * 16 + j;
                g.out[(size_t)r * H + c] = f2bf(acc[mi][ni][j]);
            }
        }
    }
}

extern "C" void kernel_launch(void* const* d_in, const int* in_sizes, int n_in,
                              void* d_out, int out_size, void* d_ws, size_t ws_size,
                              hipStream_t stream) {
    const float* x_e = (const float*)d_in[0];
    const float* x_c = (const float*)d_in[1];
    const int* e_ee = (const int*)d_in[2];
    const int* e_ec = (const int*)d_in[3];
    const int* e_ce = (const int*)d_in[4];
    const float* P_e = (const float*)d_in[5];
    const float* P_c = (const float*)d_in[6];
    const float* Wl1 = (const float*)d_in[7];
    const float* bl1 = (const float*)d_in[8];
    const float* Wr1 = (const float*)d_in[9];
    const float* Wl2 = (const float*)d_in[10];
    const float* bl2 = (const float*)d_in[11];
    const float* Wr2 = (const float*)d_in[12];
    float* out = (float*)d_out;

    const size_t EHp = (size_t)ME_PAD * H;
    const size_t CHp = (size_t)MC_PAD * H;

    u16* us = (u16*)d_ws;
    u16* he0 = us;   us += EHp;
    u16* he1 = us;   us += EHp;
    u16* aggE1 = us; us += EHp;
    u16* aggE2 = us; us += EHp;
    u16* hc0 = us;   us += CHp;
    u16* hc1 = us;   us += CHp;
    u16* aggC = us;  us += CHp;
    u16* PeT = us;   us += H * D_E;
    u16* PcT = us;   us += H * D_C;
    u16* WlT1 = us;  us += 3 * H * H;   // slices 0,1,2
    u16* WrT1_1 = us; us += H * H;
    u16* WrT1s = us;  us += H * H;      // (Wr1[0]+Wr1[2])^T
    u16* WlT2 = us;  us += 3 * H * H;
    u16* WrT2_1 = us; us += H * H;
    u16* WrT2s = us;  us += H * H;

    int* ip = (int*)us;
    int* eePtr = ip;  ip += N_E + 1;
    int* eeSrc = ip;  ip += E_EE;
    int* eeCur = ip;  ip += N_E;
    int* cePtr = ip;  ip += N_E + 1;
    int* ceSrc = ip;  ip += E_CE;
    int* ceCur = ip;  ip += N_E;
    int* ecPtr = ip;  ip += N_C + 1;
    int* ecSrc = ip;  ip += E_EC;
    int* ecCur = ip;  ip += N_C;
    int* cntAll = ip; ip += SCAN_N;
    int* part = ip;   ip += SCAN_N;
    int* bsum = ip;   ip += SCAN_NB + 1;

    const int WHH = H * H;

    // --- CSR build ---
    hipMemsetAsync(cntAll, 0, (size_t)SCAN_N * sizeof(int), stream);
    hist_k<<<(E_EE + 255) / 256, 256, 0, stream>>>(e_ee + E_EE, E_EE, cntAll);
    hist_k<<<(E_CE + 255) / 256, 256, 0, stream>>>(e_ce + E_CE, E_CE, cntAll + N_E);
    hist_k<<<(E_EC + 255) / 256, 256, 0, stream>>>(e_ec + E_EC, E_EC, cntAll + 2 * N_E);
    scan_blk_k<<<SCAN_NB, 1024, 0, stream>>>(cntAll, part, bsum);
    scan_top_k<<<1, 1024, 0, stream>>>(bsum);
    scan_out_k<<<SCAN_NB, 1024, 0, stream>>>(part, bsum, eePtr, eeCur, cePtr, ceCur, ecPtr, ecCur);
    reorder_k<<<(E_EE + 255) / 256, 256, 0, stream>>>(e_ee, e_ee + E_EE, E_EE, eeCur, eeSrc);
    reorder_k<<<(E_CE + 255) / 256, 256, 0, stream>>>(e_ce, e_ce + E_CE, E_CE, ceCur, ceSrc);
    reorder_k<<<(E_EC + 255) / 256, 256, 0, stream>>>(e_ec, e_ec + E_EC, E_EC, ecCur, ecSrc);

    // --- weight prep (transpose to [N][K] bf16; fold Wr entity pairs) ---
    {
        dim3 blk(32, 32);
        transpose_w_k<<<dim3(D_E / 32, H / 32), blk, 0, stream>>>(P_e, PeT, D_E);
        transpose_w_k<<<dim3(D_C / 32, H / 32), blk, 0, stream>>>(P_c, PcT, D_C);
        for (int p = 0; p < 3; ++p) {
            transpose_w_k<<<dim3(H / 32, H / 32), blk, 0, stream>>>(Wl1 + p * WHH, WlT1 + p * WHH, H);
            transpose_w_k<<<dim3(H / 32, H / 32), blk, 0, stream>>>(Wl2 + p * WHH, WlT2 + p * WHH, H);
        }
        transpose_w_k<<<dim3(H / 32, H / 32), blk, 0, stream>>>(Wr1 + 1 * WHH, WrT1_1, H);
        transpose_w_k<<<dim3(H / 32, H / 32), blk, 0, stream>>>(Wr2 + 1 * WHH, WrT2_1, H);
        transpose_wsum_k<<<dim3(H / 32, H / 32), blk, 0, stream>>>(Wr1 + 0 * WHH, Wr1 + 2 * WHH, WrT1s);
        transpose_wsum_k<<<dim3(H / 32, H / 32), blk, 0, stream>>>(Wr2 + 0 * WHH, Wr2 + 2 * WHH, WrT2s);
    }

    const int gridE = ME_PAD / 128, gridC = MC_PAD / 128;

    // --- projections (fp32 A read + in-kernel cvt) ---
    {
        ProjArgs g{x_e, PeT, D_E, N_E, he0};
        gemm_proj_k<<<gridE, 512, 0, stream>>>(g);
    }
    {
        ProjArgs g{x_c, PcT, D_C, N_C, hc0};
        gemm_proj_k<<<gridC, 512, 0, stream>>>(g);
    }

    // --- conv1 ---
    gather_mean_k<<<ME_PAD / 4, 256, 0, stream>>>(he0, eePtr, eeSrc, N_E, ME_PAD, aggE1);
    gather_mean_k<<<ME_PAD / 4, 256, 0, stream>>>(hc0, cePtr, ceSrc, N_E, ME_PAD, aggE2);
    gather_mean_k<<<MC_PAD / 4, 256, 0, stream>>>(he0, ecPtr, ecSrc, N_C, MC_PAD, aggC);
    {
        GemmArgs g{};
        g.A[0] = aggE1; g.Wt[0] = WlT1 + 0 * WHH;
        g.A[1] = aggE2; g.Wt[1] = WlT1 + 2 * WHH;
        g.A[2] = he0;   g.Wt[2] = WrT1s;
        g.K = H; g.nPairs = 3;
        g.bias1 = bl1 + 0 * H; g.bias2 = bl1 + 2 * H;
        g.res = he0; g.out = he1; g.mode = 1;
        gemm_bf16_k<<<gridE, 512, 0, stream>>>(g);
    }
    {
        GemmArgs g{};
        g.A[0] = aggC; g.Wt[0] = WlT1 + 1 * WHH;
        g.A[1] = hc0;  g.Wt[1] = WrT1_1;
        g.K = H; g.nPairs = 2;
        g.bias1 = bl1 + 1 * H;
        g.res = hc0; g.out = hc1; g.mode = 1;
        gemm_bf16_k<<<gridC, 512, 0, stream>>>(g);
    }

    // --- conv2 (fused l2norm, direct to d_out) ---
    gather_mean_k<<<ME_PAD / 4, 256, 0, stream>>>(he1, eePtr, eeSrc, N_E, ME_PAD, aggE1);
    gather_mean_k<<<ME_PAD / 4, 256, 0, stream>>>(hc1, cePtr, ceSrc, N_E, ME_PAD, aggE2);
    gather_mean_k<<<MC_PAD / 4, 256, 0, stream>>>(he1, ecPtr, ecSrc, N_C, MC_PAD, aggC);
    {
        GemmArgs g{};
        g.A[0] = aggE1; g.Wt[0] = WlT2 + 0 * WHH;
        g.A[1] = aggE2; g.Wt[1] = WlT2 + 2 * WHH;
        g.A[2] = he1;   g.Wt[2] = WrT2s;
        g.K = H; g.nPairs = 3;
        g.bias1 = bl2 + 0 * H; g.bias2 = bl2 + 2 * H;
        g.out = out; g.Mvalid = N_E; g.mode = 2;
        gemm_bf16_k<<<gridE, 512, 0, stream>>>(g);
    }
    {
        GemmArgs g{};
        g.A[0] = aggC; g.Wt[0] = WlT2 + 1 * WHH;
        g.A[1] = hc1;  g.Wt[1] = WrT2_1;
        g.K = H; g.nPairs = 2;
        g.bias1 = bl2 + 1 * H;
        g.out = out + (size_t)N_E * H; g.Mvalid = N_C; g.mode = 2;
        gemm_bf16_k<<<gridC, 512, 0, stream>>>(g);
    }
}

// Round 6
// 893.402 us; speedup vs baseline: 15.6341x; 1.0996x over previous
//
#include <hip/hip_runtime.h>
#include <hip/hip_bf16.h>

#define N_E 100000
#define N_C 50000
#define H 256
#define D_E 768
#define D_C 1024
#define E_EE 800000
#define E_EC 400000
#define E_CE 400000
#define E_TOT (E_EE + E_CE + E_EC)

#define ME_PAD 100096  // 782*128
#define MC_PAD 50048   // 391*128

typedef unsigned short u16;
typedef __attribute__((ext_vector_type(8))) short bf16x8;
typedef __attribute__((ext_vector_type(4))) float f32x4;

__device__ __forceinline__ float bf2f(u16 x) {
    unsigned u = ((unsigned)x) << 16;
    return __builtin_bit_cast(float, u);
}
__device__ __forceinline__ u16 f2bf(float f) {
    unsigned u = __builtin_bit_cast(unsigned, f);
    u = (u + 0x7fffu + ((u >> 16) & 1u)) >> 16;
    return (u16)u;
}

// ---------------- merged weight transpose: 12 jobs, [K][256] fp32 -> [256][K] bf16 ----------------
struct TransJobs {
    const float* a[12];
    const float* b[12];  // nullable -> added
    u16* dst[12];
    int K[12];
};

__global__ __launch_bounds__(1024) void transpose_all_k(TransJobs t) {
    int j = blockIdx.z;
    int K = t.K[j];
    int k0 = blockIdx.x * 32;
    if (k0 >= K) return;
    int n0 = blockIdx.y * 32;
    __shared__ float sm[32][33];
    int tx = threadIdx.x, ty = threadIdx.y;
    size_t idx = (size_t)(k0 + ty) * H + n0 + tx;
    float v = t.a[j][idx];
    if (t.b[j]) v += t.b[j][idx];
    sm[ty][tx] = v;
    __syncthreads();
    t.dst[j][(size_t)(n0 + ty) * K + k0 + tx] = f2bf(sm[tx][ty]);
}

// ---------------- CSR build (merged) ----------------
__global__ __launch_bounds__(256) void hist3_k(const int* __restrict__ eeD,
                                               const int* __restrict__ ceD,
                                               const int* __restrict__ ecD,
                                               int* __restrict__ cnt) {
    int i = blockIdx.x * 256 + threadIdx.x;
    if (i >= E_TOT) return;
    if (i < E_EE) atomicAdd(&cnt[eeD[i]], 1);
    else if (i < E_EE + E_CE) atomicAdd(&cnt[N_E + ceD[i - E_EE]], 1);
    else atomicAdd(&cnt[2 * N_E + ecD[i - E_EE - E_CE]], 1);
}

#define SCAN_N (2 * N_E + N_C)  // 250000
#define SCAN_NB ((SCAN_N + 1023) / 1024)

__global__ __launch_bounds__(1024) void scan_blk_k(const int* __restrict__ cnt,
                                                   int* __restrict__ part,
                                                   int* __restrict__ bsum) {
    __shared__ int sm[1024];
    int i = blockIdx.x * 1024 + threadIdx.x;
    int v = (i < SCAN_N) ? cnt[i] : 0;
    sm[threadIdx.x] = v;
    __syncthreads();
    for (int off = 1; off < 1024; off <<= 1) {
        int t = (threadIdx.x >= off) ? sm[threadIdx.x - off] : 0;
        __syncthreads();
        sm[threadIdx.x] += t;
        __syncthreads();
    }
    if (i < SCAN_N) part[i] = sm[threadIdx.x] - v;
    if (threadIdx.x == 1023) bsum[blockIdx.x] = sm[1023];
}

__global__ __launch_bounds__(1024) void scan_top_k(int* __restrict__ bsum) {
    __shared__ int sm[1024];
    int v = (threadIdx.x < SCAN_NB) ? bsum[threadIdx.x] : 0;
    sm[threadIdx.x] = v;
    __syncthreads();
    for (int off = 1; off < 1024; off <<= 1) {
        int t = (threadIdx.x >= off) ? sm[threadIdx.x - off] : 0;
        __syncthreads();
        sm[threadIdx.x] += t;
        __syncthreads();
    }
    if (threadIdx.x < SCAN_NB) bsum[threadIdx.x] = sm[threadIdx.x] - v;
}

__global__ __launch_bounds__(1024) void scan_out_k(const int* __restrict__ part,
                                                   const int* __restrict__ bsum,
                                                   int* __restrict__ eePtr,
                                                   int* __restrict__ cePtr,
                                                   int* __restrict__ ecPtr,
                                                   int* __restrict__ curAll) {
    int i = blockIdx.x * 1024 + threadIdx.x;
    if (i < SCAN_N) {
        int v = part[i] + bsum[blockIdx.x];
        int w;
        if (i < N_E) {
            w = v; eePtr[i] = w;
        } else if (i < 2 * N_E) {
            w = v - E_EE; cePtr[i - N_E] = w;
        } else {
            w = v - (E_EE + E_CE); ecPtr[i - 2 * N_E] = w;
        }
        curAll[i] = w;
    }
    if (i == 0) {
        eePtr[N_E] = E_EE;
        cePtr[N_E] = E_CE;
        ecPtr[N_C] = E_EC;
    }
}

__global__ __launch_bounds__(256) void reorder3_k(const int* __restrict__ eeS, const int* __restrict__ eeD,
                                                  const int* __restrict__ ceS, const int* __restrict__ ceD,
                                                  const int* __restrict__ ecS, const int* __restrict__ ecD,
                                                  int* __restrict__ curAll, int* __restrict__ srcAll) {
    int i = blockIdx.x * 256 + threadIdx.x;
    if (i >= E_TOT) return;
    if (i < E_EE) {
        int pos = atomicAdd(&curAll[eeD[i]], 1);
        srcAll[pos] = eeS[i];
    } else if (i < E_EE + E_CE) {
        int k = i - E_EE;
        int pos = atomicAdd(&curAll[N_E + ceD[k]], 1);
        srcAll[E_EE + pos] = ceS[k];
    } else {
        int k = i - E_EE - E_CE;
        int pos = atomicAdd(&curAll[2 * N_E + ecD[k]], 1);
        srcAll[E_EE + E_CE + pos] = ecS[k];
    }
}

// ---------------- merged gather-mean: 3 jobs per launch ----------------
// wave per dst row; 16B/lane; two edges per iteration (lane>>5 selects edge)
struct GatherArgs {
    const u16* feat[3];
    const int* rowptr[3];
    const int* srcIdx[3];
    u16* outAgg[3];
    int nDst[3];
    int blkEnd[3];  // exclusive block end per job
};

__device__ __forceinline__ void acc8(float* a, uint4 v) {
    a[0] += __builtin_bit_cast(float, v.x << 16);
    a[1] += __builtin_bit_cast(float, v.x & 0xffff0000u);
    a[2] += __builtin_bit_cast(float, v.y << 16);
    a[3] += __builtin_bit_cast(float, v.y & 0xffff0000u);
    a[4] += __builtin_bit_cast(float, v.z << 16);
    a[5] += __builtin_bit_cast(float, v.z & 0xffff0000u);
    a[6] += __builtin_bit_cast(float, v.w << 16);
    a[7] += __builtin_bit_cast(float, v.w & 0xffff0000u);
}

__global__ __launch_bounds__(256) void gather3_k(GatherArgs a) {
    const int b = blockIdx.x;
    const int j = (b >= a.blkEnd[0]) + (b >= a.blkEnd[1]);
    const int b0 = j ? a.blkEnd[j - 1] : 0;
    const int r = (b - b0) * 4 + (threadIdx.x >> 6);  // r < nPad by grid construction
    const int lane = threadIdx.x & 63;
    const int half = lane >> 5;
    const int pos = lane & 31;

    float acc[8] = {};
    int deg = 0;
    if (r < a.nDst[j]) {
        const int* __restrict__ rp = a.rowptr[j];
        const int* __restrict__ si = a.srcIdx[j];
        const u16* __restrict__ ft = a.feat[j];
        int e0 = rp[r], e1 = rp[r + 1];
        deg = e1 - e0;
        int e = e0;
        for (; e + 3 < e1; e += 4) {
            int sA = si[e + half];
            int sB = si[e + 2 + half];
            uint4 vA = *(const uint4*)(ft + (size_t)sA * H + pos * 8);
            uint4 vB = *(const uint4*)(ft + (size_t)sB * H + pos * 8);
            acc8(acc, vA);
            acc8(acc, vB);
        }
        for (; e + 1 < e1; e += 2) {
            int s = si[e + half];
            uint4 v = *(const uint4*)(ft + (size_t)s * H + pos * 8);
            acc8(acc, v);
        }
        if (e < e1 && half == 0) {
            int s = si[e];
            uint4 v = *(const uint4*)(ft + (size_t)s * H + pos * 8);
            acc8(acc, v);
        }
    }
#pragma unroll
    for (int k = 0; k < 8; ++k) acc[k] += __shfl_xor(acc[k], 32);

    if (half == 0) {
        float inv = deg > 0 ? 1.f / (float)deg : 0.f;
        uint4 o;
        o.x = (unsigned)f2bf(acc[0] * inv) | ((unsigned)f2bf(acc[1] * inv) << 16);
        o.y = (unsigned)f2bf(acc[2] * inv) | ((unsigned)f2bf(acc[3] * inv) << 16);
        o.z = (unsigned)f2bf(acc[4] * inv) | ((unsigned)f2bf(acc[5] * inv) << 16);
        o.w = (unsigned)f2bf(acc[6] * inv) | ((unsigned)f2bf(acc[7] * inv) << 16);
        *(uint4*)(a.outAgg[j] + (size_t)r * H + pos * 8) = o;
    }
}

// ================= conv GEMM (K = H = 256 compile-time), 2 configs per launch =================
// tile 128 x 256, 8 waves (2x4), wave tile 64x64, BK=32, 2-phase counted-vmcnt pipeline.
struct GemmCfg {
    const u16* A[3];
    const u16* Wt[3];
    int nPairs;
    const float* bias1;  // nullable
    const float* bias2;  // nullable
    const u16* res;      // bf16 residual (mode 1)
    void* out;           // u16 (mode 1) or float (mode 2)
    int Mvalid;          // mode 2 store guard
    int mode;            // 1 = relu(acc+b)+res -> bf16 ; 2 = l2norm(acc+b) -> fp32
};
struct ConvArgs2 {
    GemmCfg c[2];
    int blkSplit;
};

__global__ __launch_bounds__(512, 4) void gemm_conv_k(ConvArgs2 gg) {
    const int which = blockIdx.x >= gg.blkSplit;
    const GemmCfg* __restrict__ g = which ? &gg.c[1] : &gg.c[0];
    const int row0 = (blockIdx.x - (which ? gg.blkSplit : 0)) * 128;

    __shared__ char lds[2][24576];
    __shared__ float rowsq[128];
    const int tid = threadIdx.x;
    const int lane = tid & 63;
    const int wid = tid >> 6;
    const int wm = wid >> 2;
    const int wn = wid & 3;

    // staging source offsets (inverse-swizzled; linear LDS dest per rule #21)
    const int srow = tid >> 2;
    const int au = (tid & 3) ^ ((srow >> 1) & 3);
    const int ofsA = (row0 + srow) * H + au * 8;
    const int ofsB1 = srow * H + au * 8;
    const int brow2 = 128 + srow;
    const int bu2 = (tid & 3) ^ ((brow2 >> 1) & 3);
    const int ofsB2 = brow2 * H + bu2 * 8;

    int a_off[4], b_off[4];
#pragma unroll
    for (int mi = 0; mi < 4; ++mi) {
        int row = wm * 64 + mi * 16 + (lane & 15);
        int u = (lane >> 4) ^ ((row >> 1) & 3);
        a_off[mi] = row * 64 + u * 16;
    }
#pragma unroll
    for (int ni = 0; ni < 4; ++ni) {
        int row = wn * 64 + ni * 16 + (lane & 15);
        int u = (lane >> 4) ^ ((row >> 1) & 3);
        b_off[ni] = 8192 + row * 64 + u * 16;
    }

#define STAGE(p_, kk_, ph_)                                                                       \
    do {                                                                                          \
        const u16* A_ = g->A[p_];                                                                 \
        const u16* W_ = g->Wt[p_];                                                                \
        __builtin_amdgcn_global_load_lds(                                                         \
            (const __attribute__((address_space(1))) void*)(A_ + ofsA + (kk_)),                   \
            (__attribute__((address_space(3))) void*)(lds[ph_] + wid * 1024), 16, 0, 0);          \
        __builtin_amdgcn_global_load_lds(                                                         \
            (const __attribute__((address_space(1))) void*)(W_ + ofsB1 + (kk_)),                  \
            (__attribute__((address_space(3))) void*)(lds[ph_] + 8192 + wid * 1024), 16, 0, 0);   \
        __builtin_amdgcn_global_load_lds(                                                         \
            (const __attribute__((address_space(1))) void*)(W_ + ofsB2 + (kk_)),                  \
            (__attribute__((address_space(3))) void*)(lds[ph_] + 16384 + wid * 1024), 16, 0, 0);  \
    } while (0)

    f32x4 acc[4][4] = {};
    const int T = g->nPairs * (H >> 5);

    STAGE(0, 0, 0);
    int pn = 0, kn = 32;
    if (kn == H) { kn = 0; pn = 1; }

    for (int s = 0; s < T; ++s) {
        const int ph = s & 1;
        if (s + 1 < T) {
            STAGE(pn, kn, ph ^ 1);
            kn += 32;
            if (kn == H) { kn = 0; ++pn; }
            asm volatile("s_waitcnt vmcnt(3)" ::: "memory");
        } else {
            asm volatile("s_waitcnt vmcnt(0)" ::: "memory");
        }
        __builtin_amdgcn_sched_barrier(0);
        __builtin_amdgcn_s_barrier();

        bf16x8 af[4], bfr[4];
#pragma unroll
        for (int mi = 0; mi < 4; ++mi)
            af[mi] = *reinterpret_cast<const bf16x8*>(lds[ph] + a_off[mi]);
#pragma unroll
        for (int ni = 0; ni < 4; ++ni)
            bfr[ni] = *reinterpret_cast<const bf16x8*>(lds[ph] + b_off[ni]);
#pragma unroll
        for (int mi = 0; mi < 4; ++mi)
#pragma unroll
            for (int ni = 0; ni < 4; ++ni)
                acc[mi][ni] = __builtin_amdgcn_mfma_f32_16x16x32_bf16(af[mi], bfr[ni],
                                                                      acc[mi][ni], 0, 0, 0);
        __builtin_amdgcn_sched_barrier(0);
        __builtin_amdgcn_s_barrier();
    }
#undef STAGE

    // ---- epilogue: D mapping col = lane&15, row = (lane>>4)*4 + j ----
    const int ccol = wn * 64 + (lane & 15);
    const int crow0 = row0 + wm * 64 + ((lane >> 4) << 2);
    float bv[4];
#pragma unroll
    for (int ni = 0; ni < 4; ++ni) {
        int c = ccol + ni * 16;
        float b = 0.f;
        if (g->bias1) b += g->bias1[c];
        if (g->bias2) b += g->bias2[c];
        bv[ni] = b;
    }

    if (g->mode == 1) {
#pragma unroll
        for (int ni = 0; ni < 4; ++ni) {
            int c = ccol + ni * 16;
#pragma unroll
            for (int mi = 0; mi < 4; ++mi) {
#pragma unroll
                for (int j = 0; j < 4; ++j) {
                    int r = crow0 + mi * 16 + j;
                    size_t idx = (size_t)r * H + c;
                    float v = fmaxf(acc[mi][ni][j] + bv[ni], 0.f) + bf2f(g->res[idx]);
                    ((u16*)g->out)[idx] = f2bf(v);
                }
            }
        }
    } else {
        if (tid < 128) rowsq[tid] = 0.f;
        __syncthreads();
#pragma unroll
        for (int mi = 0; mi < 4; ++mi) {
#pragma unroll
            for (int j = 0; j < 4; ++j) {
                float p = 0.f;
#pragma unroll
                for (int ni = 0; ni < 4; ++ni) {
                    float v = acc[mi][ni][j] + bv[ni];
                    p += v * v;
                }
                p += __shfl_xor(p, 1);
                p += __shfl_xor(p, 2);
                p += __shfl_xor(p, 4);
                p += __shfl_xor(p, 8);
                if ((lane & 15) == 0) {
                    int rl = wm * 64 + mi * 16 + ((lane >> 4) << 2) + j;
                    atomicAdd(&rowsq[rl], p);
                }
            }
        }
        __syncthreads();
#pragma unroll
        for (int mi = 0; mi < 4; ++mi) {
#pragma unroll
            for (int j = 0; j < 4; ++j) {
                int rl = wm * 64 + mi * 16 + ((lane >> 4) << 2) + j;
                int r = row0 + rl;
                if (r < g->Mvalid) {
                    float inv = 1.f / fmaxf(sqrtf(rowsq[rl]), 1e-12f);
#pragma unroll
                    for (int ni = 0; ni < 4; ++ni) {
                        int c = ccol + ni * 16;
                        float v = acc[mi][ni][j] + bv[ni];
                        ((float*)g->out)[(size_t)r * H + c] = v * inv;
                    }
                }
            }
        }
    }
}

// ================= projection GEMM: fp32 A (in-kernel cvt), bf16 Wt; 2 configs =================
struct ProjArgs2 {
    const float* A[2];
    const u16* Wt[2];
    int K[2];
    int M[2];
    u16* out[2];
    int blkSplit;
};

__global__ __launch_bounds__(512, 4) void gemm_proj_k(ProjArgs2 gg) {
    const int which = blockIdx.x >= gg.blkSplit;
    const int row0 = (blockIdx.x - (which ? gg.blkSplit : 0)) * 128;
    const float* __restrict__ Aptr = gg.A[which];
    const u16* __restrict__ Wt = gg.Wt[which];
    const int K = gg.K[which];
    const int M = gg.M[which];
    u16* __restrict__ outp = gg.out[which];

    __shared__ char lds[2][24576];
    const int tid = threadIdx.x;
    const int lane = tid & 63;
    const int wid = tid >> 6;
    const int wm = wid >> 2;
    const int wn = wid & 3;

    const int srow = tid >> 2;
    const int cunit = tid & 3;
    const int aRow = min(row0 + srow, M - 1);
    const float* pA = Aptr + (size_t)aRow * K + cunit * 8;
    const int aDst = srow * 64 + (cunit ^ ((srow >> 1) & 3)) * 16;

    const int bu1 = cunit ^ ((srow >> 1) & 3);
    const int ofsB1 = srow * K + bu1 * 8;
    const int brow2 = 128 + srow;
    const int bu2 = cunit ^ ((brow2 >> 1) & 3);
    const int ofsB2 = brow2 * K + bu2 * 8;

    int a_off[4], b_off[4];
#pragma unroll
    for (int mi = 0; mi < 4; ++mi) {
        int row = wm * 64 + mi * 16 + (lane & 15);
        int u = (lane >> 4) ^ ((row >> 1) & 3);
        a_off[mi] = row * 64 + u * 16;
    }
#pragma unroll
    for (int ni = 0; ni < 4; ++ni) {
        int row = wn * 64 + ni * 16 + (lane & 15);
        int u = (lane >> 4) ^ ((row >> 1) & 3);
        b_off[ni] = 8192 + row * 64 + u * 16;
    }

#define BSTAGE(kk_, ph_)                                                                          \
    do {                                                                                          \
        __builtin_amdgcn_global_load_lds(                                                         \
            (const __attribute__((address_space(1))) void*)(Wt + ofsB1 + (kk_)),                  \
            (__attribute__((address_space(3))) void*)(lds[ph_] + 8192 + wid * 1024), 16, 0, 0);   \
        __builtin_amdgcn_global_load_lds(                                                         \
            (const __attribute__((address_space(1))) void*)(Wt + ofsB2 + (kk_)),                  \
            (__attribute__((address_space(3))) void*)(lds[ph_] + 16384 + wid * 1024), 16, 0, 0);  \
    } while (0)

    f32x4 acc[4][4] = {};
    const int T = K >> 5;

    BSTAGE(0, 0);
    float4 c0 = *reinterpret_cast<const float4*>(pA);
    float4 c1 = *reinterpret_cast<const float4*>(pA + 4);

    for (int s = 0; s < T; ++s) {
        const int ph = s & 1;
        float4 n0 = make_float4(0.f, 0.f, 0.f, 0.f), n1 = n0;
        if (s + 1 < T) {
            BSTAGE((s + 1) * 32, ph ^ 1);
            n0 = *reinterpret_cast<const float4*>(pA + (s + 1) * 32);
            n1 = *reinterpret_cast<const float4*>(pA + (s + 1) * 32 + 4);
        }
        union { bf16x8 v; u16 e[8]; } pk;
        pk.e[0] = f2bf(c0.x); pk.e[1] = f2bf(c0.y); pk.e[2] = f2bf(c0.z); pk.e[3] = f2bf(c0.w);
        pk.e[4] = f2bf(c1.x); pk.e[5] = f2bf(c1.y); pk.e[6] = f2bf(c1.z); pk.e[7] = f2bf(c1.w);
        *reinterpret_cast<bf16x8*>(lds[ph] + aDst) = pk.v;
        asm volatile("s_waitcnt lgkmcnt(0)" ::: "memory");
        __builtin_amdgcn_sched_barrier(0);
        __builtin_amdgcn_s_barrier();

        bf16x8 af[4], bfr[4];
#pragma unroll
        for (int mi = 0; mi < 4; ++mi)
            af[mi] = *reinterpret_cast<const bf16x8*>(lds[ph] + a_off[mi]);
#pragma unroll
        for (int ni = 0; ni < 4; ++ni)
            bfr[ni] = *reinterpret_cast<const bf16x8*>(lds[ph] + b_off[ni]);
#pragma unroll
        for (int mi = 0; mi < 4; ++mi)
#pragma unroll
            for (int ni = 0; ni < 4; ++ni)
                acc[mi][ni] = __builtin_amdgcn_mfma_f32_16x16x32_bf16(af[mi], bfr[ni],
                                                                      acc[mi][ni], 0, 0, 0);
        __builtin_amdgcn_sched_barrier(0);
        __builtin_amdgcn_s_barrier();
        c0 = n0; c1 = n1;
    }
#undef BSTAGE

    const int ccol = wn * 64 + (lane & 15);
    const int crow0 = row0 + wm * 64 + ((lane >> 4) << 2);
#pragma unroll
    for (int ni = 0; ni < 4; ++ni) {
        int c = ccol + ni * 16;
#pragma unroll
        for (int mi = 0; mi < 4; ++mi) {
#pragma unroll
            for (int j = 0; j < 4; ++j) {
                int r = crow0 + mi * 16 + j;
                outp[(size_t)r * H + c] = f2bf(acc[mi][ni][j]);
            }
        }
    }
}

extern "C" void kernel_launch(void* const* d_in, const int* in_sizes, int n_in,
                              void* d_out, int out_size, void* d_ws, size_t ws_size,
                              hipStream_t stream) {
    const float* x_e = (const float*)d_in[0];
    const float* x_c = (const float*)d_in[1];
    const int* e_ee = (const int*)d_in[2];
    const int* e_ec = (const int*)d_in[3];
    const int* e_ce = (const int*)d_in[4];
    const float* P_e = (const float*)d_in[5];
    const float* P_c = (const float*)d_in[6];
    const float* Wl1 = (const float*)d_in[7];
    const float* bl1 = (const float*)d_in[8];
    const float* Wr1 = (const float*)d_in[9];
    const float* Wl2 = (const float*)d_in[10];
    const float* bl2 = (const float*)d_in[11];
    const float* Wr2 = (const float*)d_in[12];
    float* out = (float*)d_out;

    const size_t EHp = (size_t)ME_PAD * H;
    const size_t CHp = (size_t)MC_PAD * H;

    u16* us = (u16*)d_ws;
    u16* he0 = us;   us += EHp;
    u16* he1 = us;   us += EHp;
    u16* aggE1 = us; us += EHp;
    u16* aggE2 = us; us += EHp;
    u16* hc0 = us;   us += CHp;
    u16* hc1 = us;   us += CHp;
    u16* aggC = us;  us += CHp;
    u16* PeT = us;   us += H * D_E;
    u16* PcT = us;   us += H * D_C;
    u16* WlT1 = us;  us += 3 * H * H;
    u16* WrT1_1 = us; us += H * H;
    u16* WrT1s = us;  us += H * H;
    u16* WlT2 = us;  us += 3 * H * H;
    u16* WrT2_1 = us; us += H * H;
    u16* WrT2s = us;  us += H * H;

    int* ip = (int*)us;
    int* eePtr = ip;  ip += N_E + 1;
    int* cePtr = ip;  ip += N_E + 1;
    int* ecPtr = ip;  ip += N_C + 1;
    int* curAll = ip; ip += SCAN_N;
    int* srcAll = ip; ip += E_TOT;
    int* cntAll = ip; ip += SCAN_N;
    int* part = ip;   ip += SCAN_N;
    int* bsum = ip;   ip += SCAN_NB + 1;

    const int WHH = H * H;

    // --- CSR build (1 hist + 3 scan + 1 reorder) ---
    hipMemsetAsync(cntAll, 0, (size_t)SCAN_N * sizeof(int), stream);
    hist3_k<<<(E_TOT + 255) / 256, 256, 0, stream>>>(e_ee + E_EE, e_ce + E_CE, e_ec + E_EC, cntAll);
    scan_blk_k<<<SCAN_NB, 1024, 0, stream>>>(cntAll, part, bsum);
    scan_top_k<<<1, 1024, 0, stream>>>(bsum);
    scan_out_k<<<SCAN_NB, 1024, 0, stream>>>(part, bsum, eePtr, cePtr, ecPtr, curAll);
    reorder3_k<<<(E_TOT + 255) / 256, 256, 0, stream>>>(e_ee, e_ee + E_EE, e_ce, e_ce + E_CE,
                                                        e_ec, e_ec + E_EC, curAll, srcAll);
    const int* eeSrc = srcAll;
    const int* ceSrc = srcAll + E_EE;
    const int* ecSrc = srcAll + E_EE + E_CE;

    // --- weight prep: 12 transpose jobs in one launch ---
    {
        TransJobs t{};
        int n = 0;
        auto add = [&](const float* a, const float* b, u16* d, int K) {
            t.a[n] = a; t.b[n] = b; t.dst[n] = d; t.K[n] = K; ++n;
        };
        add(P_e, nullptr, PeT, D_E);
        add(P_c, nullptr, PcT, D_C);
        for (int p = 0; p < 3; ++p) add(Wl1 + p * WHH, nullptr, WlT1 + p * WHH, H);
        for (int p = 0; p < 3; ++p) add(Wl2 + p * WHH, nullptr, WlT2 + p * WHH, H);
        add(Wr1 + 1 * WHH, nullptr, WrT1_1, H);
        add(Wr2 + 1 * WHH, nullptr, WrT2_1, H);
        add(Wr1 + 0 * WHH, Wr1 + 2 * WHH, WrT1s, H);
        add(Wr2 + 0 * WHH, Wr2 + 2 * WHH, WrT2s, H);
        transpose_all_k<<<dim3(D_C / 32, H / 32, 12), dim3(32, 32), 0, stream>>>(t);
    }

    const int gridE = ME_PAD / 128, gridC = MC_PAD / 128;

    // --- projections (merged) ---
    {
        ProjArgs2 g{};
        g.A[0] = x_e; g.Wt[0] = PeT; g.K[0] = D_E; g.M[0] = N_E; g.out[0] = he0;
        g.A[1] = x_c; g.Wt[1] = PcT; g.K[1] = D_C; g.M[1] = N_C; g.out[1] = hc0;
        g.blkSplit = gridE;
        gemm_proj_k<<<gridE + gridC, 512, 0, stream>>>(g);
    }

    const int gBlkE = ME_PAD / 4, gBlkC = MC_PAD / 4;
    const int gTotal = 2 * gBlkE + gBlkC;

    // --- conv1 ---
    {
        GatherArgs a{};
        a.feat[0] = he0; a.rowptr[0] = eePtr; a.srcIdx[0] = eeSrc; a.outAgg[0] = aggE1; a.nDst[0] = N_E;
        a.feat[1] = hc0; a.rowptr[1] = cePtr; a.srcIdx[1] = ceSrc; a.outAgg[1] = aggE2; a.nDst[1] = N_E;
        a.feat[2] = he0; a.rowptr[2] = ecPtr; a.srcIdx[2] = ecSrc; a.outAgg[2] = aggC;  a.nDst[2] = N_C;
        a.blkEnd[0] = gBlkE; a.blkEnd[1] = 2 * gBlkE; a.blkEnd[2] = gTotal;
        gather3_k<<<gTotal, 256, 0, stream>>>(a);
    }
    {
        ConvArgs2 g{};
        g.c[0].A[0] = aggE1; g.c[0].Wt[0] = WlT1 + 0 * WHH;
        g.c[0].A[1] = aggE2; g.c[0].Wt[1] = WlT1 + 2 * WHH;
        g.c[0].A[2] = he0;   g.c[0].Wt[2] = WrT1s;
        g.c[0].nPairs = 3;
        g.c[0].bias1 = bl1 + 0 * H; g.c[0].bias2 = bl1 + 2 * H;
        g.c[0].res = he0; g.c[0].out = he1; g.c[0].mode = 1;
        g.c[1].A[0] = aggC; g.c[1].Wt[0] = WlT1 + 1 * WHH;
        g.c[1].A[1] = hc0;  g.c[1].Wt[1] = WrT1_1;
        g.c[1].nPairs = 2;
        g.c[1].bias1 = bl1 + 1 * H;
        g.c[1].res = hc0; g.c[1].out = hc1; g.c[1].mode = 1;
        g.blkSplit = gridE;
        gemm_conv_k<<<gridE + gridC, 512, 0, stream>>>(g);
    }

    // --- conv2 (fused l2norm, direct to d_out) ---
    {
        GatherArgs a{};
        a.feat[0] = he1; a.rowptr[0] = eePtr; a.srcIdx[0] = eeSrc; a.outAgg[0] = aggE1; a.nDst[0] = N_E;
        a.feat[1] = hc1; a.rowptr[1] = cePtr; a.srcIdx[1] = ceSrc; a.outAgg[1] = aggE2; a.nDst[1] = N_E;
        a.feat[2] = he1; a.rowptr[2] = ecPtr; a.srcIdx[2] = ecSrc; a.outAgg[2] = aggC;  a.nDst[2] = N_C;
        a.blkEnd[0] = gBlkE; a.blkEnd[1] = 2 * gBlkE; a.blkEnd[2] = gTotal;
        gather3_k<<<gTotal, 256, 0, stream>>>(a);
    }
    {
        ConvArgs2 g{};
        g.c[0].A[0] = aggE1; g.c[0].Wt[0] = WlT2 + 0 * WHH;
        g.c[0].A[1] = aggE2; g.c[0].Wt[1] = WlT2 + 2 * WHH;
        g.c[0].A[2] = he1;   g.c[0].Wt[2] = WrT2s;
        g.c[0].nPairs = 3;
        g.c[0].bias1 = bl2 + 0 * H; g.c[0].bias2 = bl2 + 2 * H;
        g.c[0].out = out; g.c[0].Mvalid = N_E; g.c[0].mode = 2;
        g.c[1].A[0] = aggC; g.c[1].Wt[0] = WlT2 + 1 * WHH;
        g.c[1].A[1] = hc1;  g.c[1].Wt[1] = WrT2_1;
        g.c[1].nPairs = 2;
        g.c[1].bias1 = bl2 + 1 * H;
        g.c[1].out = out + (size_t)N_E * H; g.c[1].Mvalid = N_C; g.c[1].mode = 2;
        g.blkSplit = gridE;
        gemm_conv_k<<<gridE + gridC, 512, 0, stream>>>(g);
    }
}

// Round 7
// 869.000 us; speedup vs baseline: 16.0731x; 1.0281x over previous
//
#include <hip/hip_runtime.h>
#include <hip/hip_bf16.h>

#define N_E 100000
#define N_C 50000
#define H 256
#define D_E 768
#define D_C 1024
#define E_EE 800000
#define E_EC 400000
#define E_CE 400000
#define E_TOT (E_EE + E_CE + E_EC)

#define ME_PAD 100096  // 782*128
#define MC_PAD 50048   // 391*128

#define LDSZ 24576  // per-phase LDS: A 8KB @0 | B 16KB @8192

typedef unsigned short u16;
typedef __attribute__((ext_vector_type(8))) short bf16x8;
typedef __attribute__((ext_vector_type(4))) float f32x4;

__device__ __forceinline__ float bf2f(u16 x) {
    unsigned u = ((unsigned)x) << 16;
    return __builtin_bit_cast(float, u);
}
__device__ __forceinline__ u16 f2bf(float f) {
    unsigned u = __builtin_bit_cast(unsigned, f);
    u = (u + 0x7fffu + ((u >> 16) & 1u)) >> 16;
    return (u16)u;
}

// ---------------- merged weight transpose: 12 jobs, [K][256] fp32 -> [256][K] bf16 ----------------
struct TransJobs {
    const float* a[12];
    const float* b[12];  // nullable -> added
    u16* dst[12];
    int K[12];
};

__global__ __launch_bounds__(1024) void transpose_all_k(TransJobs t) {
    int j = blockIdx.z;
    int K = t.K[j];
    int k0 = blockIdx.x * 32;
    if (k0 >= K) return;
    int n0 = blockIdx.y * 32;
    __shared__ float sm[32][33];
    int tx = threadIdx.x, ty = threadIdx.y;
    size_t idx = (size_t)(k0 + ty) * H + n0 + tx;
    float v = t.a[j][idx];
    if (t.b[j]) v += t.b[j][idx];
    sm[ty][tx] = v;
    __syncthreads();
    t.dst[j][(size_t)(n0 + ty) * K + k0 + tx] = f2bf(sm[tx][ty]);
}

// ---------------- CSR build (merged) ----------------
__global__ __launch_bounds__(256) void hist3_k(const int* __restrict__ eeD,
                                               const int* __restrict__ ceD,
                                               const int* __restrict__ ecD,
                                               int* __restrict__ cnt) {
    int i = blockIdx.x * 256 + threadIdx.x;
    if (i >= E_TOT) return;
    if (i < E_EE) atomicAdd(&cnt[eeD[i]], 1);
    else if (i < E_EE + E_CE) atomicAdd(&cnt[N_E + ceD[i - E_EE]], 1);
    else atomicAdd(&cnt[2 * N_E + ecD[i - E_EE - E_CE]], 1);
}

#define SCAN_N (2 * N_E + N_C)  // 250000
#define SCAN_NB ((SCAN_N + 1023) / 1024)

__global__ __launch_bounds__(1024) void scan_blk_k(const int* __restrict__ cnt,
                                                   int* __restrict__ part,
                                                   int* __restrict__ bsum) {
    __shared__ int sm[1024];
    int i = blockIdx.x * 1024 + threadIdx.x;
    int v = (i < SCAN_N) ? cnt[i] : 0;
    sm[threadIdx.x] = v;
    __syncthreads();
    for (int off = 1; off < 1024; off <<= 1) {
        int t = (threadIdx.x >= off) ? sm[threadIdx.x - off] : 0;
        __syncthreads();
        sm[threadIdx.x] += t;
        __syncthreads();
    }
    if (i < SCAN_N) part[i] = sm[threadIdx.x] - v;
    if (threadIdx.x == 1023) bsum[blockIdx.x] = sm[1023];
}

__global__ __launch_bounds__(1024) void scan_top_k(int* __restrict__ bsum) {
    __shared__ int sm[1024];
    int v = (threadIdx.x < SCAN_NB) ? bsum[threadIdx.x] : 0;
    sm[threadIdx.x] = v;
    __syncthreads();
    for (int off = 1; off < 1024; off <<= 1) {
        int t = (threadIdx.x >= off) ? sm[threadIdx.x - off] : 0;
        __syncthreads();
        sm[threadIdx.x] += t;
        __syncthreads();
    }
    if (threadIdx.x < SCAN_NB) bsum[threadIdx.x] = sm[threadIdx.x] - v;
}

__global__ __launch_bounds__(1024) void scan_out_k(const int* __restrict__ part,
                                                   const int* __restrict__ bsum,
                                                   int* __restrict__ eePtr,
                                                   int* __restrict__ cePtr,
                                                   int* __restrict__ ecPtr,
                                                   int* __restrict__ curAll) {
    int i = blockIdx.x * 1024 + threadIdx.x;
    if (i < SCAN_N) {
        int v = part[i] + bsum[blockIdx.x];
        int w;
        if (i < N_E) {
            w = v; eePtr[i] = w;
        } else if (i < 2 * N_E) {
            w = v - E_EE; cePtr[i - N_E] = w;
        } else {
            w = v - (E_EE + E_CE); ecPtr[i - 2 * N_E] = w;
        }
        curAll[i] = w;
    }
    if (i == 0) {
        eePtr[N_E] = E_EE;
        cePtr[N_E] = E_CE;
        ecPtr[N_C] = E_EC;
    }
}

__global__ __launch_bounds__(256) void reorder3_k(const int* __restrict__ eeS, const int* __restrict__ eeD,
                                                  const int* __restrict__ ceS, const int* __restrict__ ceD,
                                                  const int* __restrict__ ecS, const int* __restrict__ ecD,
                                                  int* __restrict__ curAll, int* __restrict__ srcAll) {
    int i = blockIdx.x * 256 + threadIdx.x;
    if (i >= E_TOT) return;
    if (i < E_EE) {
        int pos = atomicAdd(&curAll[eeD[i]], 1);
        srcAll[pos] = eeS[i];
    } else if (i < E_EE + E_CE) {
        int k = i - E_EE;
        int pos = atomicAdd(&curAll[N_E + ceD[k]], 1);
        srcAll[E_EE + pos] = ceS[k];
    } else {
        int k = i - E_EE - E_CE;
        int pos = atomicAdd(&curAll[2 * N_E + ecD[k]], 1);
        srcAll[E_EE + E_CE + pos] = ecS[k];
    }
}

// ---------------- merged gather-mean: 3 jobs per launch ----------------
struct GatherArgs {
    const u16* feat[3];
    const int* rowptr[3];
    const int* srcIdx[3];
    u16* outAgg[3];
    int nDst[3];
    int blkEnd[3];
};

__device__ __forceinline__ void acc8(float* a, uint4 v) {
    a[0] += __builtin_bit_cast(float, v.x << 16);
    a[1] += __builtin_bit_cast(float, v.x & 0xffff0000u);
    a[2] += __builtin_bit_cast(float, v.y << 16);
    a[3] += __builtin_bit_cast(float, v.y & 0xffff0000u);
    a[4] += __builtin_bit_cast(float, v.z << 16);
    a[5] += __builtin_bit_cast(float, v.z & 0xffff0000u);
    a[6] += __builtin_bit_cast(float, v.w << 16);
    a[7] += __builtin_bit_cast(float, v.w & 0xffff0000u);
}

__global__ __launch_bounds__(256) void gather3_k(GatherArgs a) {
    const int b = blockIdx.x;
    const int j = (b >= a.blkEnd[0]) + (b >= a.blkEnd[1]);
    const int b0 = j ? a.blkEnd[j - 1] : 0;
    const int r = (b - b0) * 4 + (threadIdx.x >> 6);
    const int lane = threadIdx.x & 63;
    const int half = lane >> 5;
    const int pos = lane & 31;

    float acc[8] = {};
    int deg = 0;
    if (r < a.nDst[j]) {
        const int* __restrict__ rp = a.rowptr[j];
        const int* __restrict__ si = a.srcIdx[j];
        const u16* __restrict__ ft = a.feat[j];
        int e0 = rp[r], e1 = rp[r + 1];
        deg = e1 - e0;
        int e = e0;
        for (; e + 7 < e1; e += 8) {  // 8 edges in flight (4 loads/lane-half)
            int sA = si[e + half];
            int sB = si[e + 2 + half];
            int sC = si[e + 4 + half];
            int sD = si[e + 6 + half];
            uint4 vA = *(const uint4*)(ft + (size_t)sA * H + pos * 8);
            uint4 vB = *(const uint4*)(ft + (size_t)sB * H + pos * 8);
            uint4 vC = *(const uint4*)(ft + (size_t)sC * H + pos * 8);
            uint4 vD = *(const uint4*)(ft + (size_t)sD * H + pos * 8);
            acc8(acc, vA); acc8(acc, vB); acc8(acc, vC); acc8(acc, vD);
        }
        for (; e + 3 < e1; e += 4) {
            int sA = si[e + half];
            int sB = si[e + 2 + half];
            uint4 vA = *(const uint4*)(ft + (size_t)sA * H + pos * 8);
            uint4 vB = *(const uint4*)(ft + (size_t)sB * H + pos * 8);
            acc8(acc, vA); acc8(acc, vB);
        }
        for (; e + 1 < e1; e += 2) {
            int s = si[e + half];
            uint4 v = *(const uint4*)(ft + (size_t)s * H + pos * 8);
            acc8(acc, v);
        }
        if (e < e1 && half == 0) {
            int s = si[e];
            uint4 v = *(const uint4*)(ft + (size_t)s * H + pos * 8);
            acc8(acc, v);
        }
    }
#pragma unroll
    for (int k = 0; k < 8; ++k) acc[k] += __shfl_xor(acc[k], 32);

    if (half == 0) {
        float inv = deg > 0 ? 1.f / (float)deg : 0.f;
        uint4 o;
        o.x = (unsigned)f2bf(acc[0] * inv) | ((unsigned)f2bf(acc[1] * inv) << 16);
        o.y = (unsigned)f2bf(acc[2] * inv) | ((unsigned)f2bf(acc[3] * inv) << 16);
        o.z = (unsigned)f2bf(acc[4] * inv) | ((unsigned)f2bf(acc[5] * inv) << 16);
        o.w = (unsigned)f2bf(acc[6] * inv) | ((unsigned)f2bf(acc[7] * inv) << 16);
        *(uint4*)(a.outAgg[j] + (size_t)r * H + pos * 8) = o;
    }
}

// ================= conv GEMM (K=H=256), triple-buffered 2-deep pipeline =================
struct GemmCfg {
    const u16* A[3];
    const u16* Wt[3];
    int nPairs;
    const float* bias1;
    const float* bias2;
    const u16* res;
    void* out;
    int Mvalid;
    int mode;  // 1 = relu(acc+b)+res -> bf16 ; 2 = l2norm(acc+b) -> fp32
};
struct ConvArgs2 {
    GemmCfg c[2];
    int blkSplit;
};

__global__ __launch_bounds__(512, 4) void gemm_conv_k(ConvArgs2 gg) {
    const int which = blockIdx.x >= gg.blkSplit;
    const GemmCfg* __restrict__ g = which ? &gg.c[1] : &gg.c[0];
    const int row0 = (blockIdx.x - (which ? gg.blkSplit : 0)) * 128;

    __shared__ char lds[3][LDSZ];
    __shared__ float rowsq[128];
    const int tid = threadIdx.x;
    const int lane = tid & 63;
    const int wid = tid >> 6;
    const int wm = wid >> 2;
    const int wn = wid & 3;

    const int srow = tid >> 2;
    const int au = (tid & 3) ^ ((srow >> 1) & 3);
    const int ofsA = (row0 + srow) * H + au * 8;
    const int ofsB1 = srow * H + au * 8;
    const int brow2 = 128 + srow;
    const int bu2 = (tid & 3) ^ ((brow2 >> 1) & 3);
    const int ofsB2 = brow2 * H + bu2 * 8;

    int a_off[4], b_off[4];
#pragma unroll
    for (int mi = 0; mi < 4; ++mi) {
        int row = wm * 64 + mi * 16 + (lane & 15);
        int u = (lane >> 4) ^ ((row >> 1) & 3);
        a_off[mi] = row * 64 + u * 16;
    }
#pragma unroll
    for (int ni = 0; ni < 4; ++ni) {
        int row = wn * 64 + ni * 16 + (lane & 15);
        int u = (lane >> 4) ^ ((row >> 1) & 3);
        b_off[ni] = 8192 + row * 64 + u * 16;
    }

#define STAGE(p_, kk_, buf_)                                                                      \
    do {                                                                                          \
        const u16* A_ = g->A[p_];                                                                 \
        const u16* W_ = g->Wt[p_];                                                                \
        __builtin_amdgcn_global_load_lds(                                                         \
            (const __attribute__((address_space(1))) void*)(A_ + ofsA + (kk_)),                   \
            (__attribute__((address_space(3))) void*)((buf_) + wid * 1024), 16, 0, 0);            \
        __builtin_amdgcn_global_load_lds(                                                         \
            (const __attribute__((address_space(1))) void*)(W_ + ofsB1 + (kk_)),                  \
            (__attribute__((address_space(3))) void*)((buf_) + 8192 + wid * 1024), 16, 0, 0);     \
        __builtin_amdgcn_global_load_lds(                                                         \
            (const __attribute__((address_space(1))) void*)(W_ + ofsB2 + (kk_)),                  \
            (__attribute__((address_space(3))) void*)((buf_) + 16384 + wid * 1024), 16, 0, 0);    \
    } while (0)

    f32x4 acc[4][4] = {};
    const int T = g->nPairs * (H >> 5);

    char* bufC = lds[0];  // compute buffer (step s)
    char* bufN = lds[1];  // step s+1
    char* bufS = lds[2];  // stage target (step s+2)

    // prologue: steps 0 and 1
    STAGE(0, 0, bufC);
    STAGE(0, 32, bufN);
    int pn = 0, kn = 64;  // next step to issue = 2
    if (kn == H) { kn = 0; pn = 1; }

    for (int s = 0; s < T; ++s) {
        if (s + 2 < T) {
            STAGE(pn, kn, bufS);
            kn += 32;
            if (kn == H) { kn = 0; ++pn; }
            asm volatile("s_waitcnt vmcnt(6)" ::: "memory");
        } else if (s + 1 < T) {
            asm volatile("s_waitcnt vmcnt(3)" ::: "memory");
        } else {
            asm volatile("s_waitcnt vmcnt(0)" ::: "memory");
        }
        __builtin_amdgcn_sched_barrier(0);
        __builtin_amdgcn_s_barrier();

        bf16x8 af[4], bfr[4];
#pragma unroll
        for (int mi = 0; mi < 4; ++mi)
            af[mi] = *reinterpret_cast<const bf16x8*>(bufC + a_off[mi]);
#pragma unroll
        for (int ni = 0; ni < 4; ++ni)
            bfr[ni] = *reinterpret_cast<const bf16x8*>(bufC + b_off[ni]);
#pragma unroll
        for (int mi = 0; mi < 4; ++mi)
#pragma unroll
            for (int ni = 0; ni < 4; ++ni)
                acc[mi][ni] = __builtin_amdgcn_mfma_f32_16x16x32_bf16(af[mi], bfr[ni],
                                                                      acc[mi][ni], 0, 0, 0);
        __builtin_amdgcn_sched_barrier(0);
        __builtin_amdgcn_s_barrier();
        char* t = bufC; bufC = bufN; bufN = bufS; bufS = t;
    }
#undef STAGE

    // ---- epilogue ----
    const int ccol = wn * 64 + (lane & 15);
    const int crow0 = row0 + wm * 64 + ((lane >> 4) << 2);
    float bv[4];
#pragma unroll
    for (int ni = 0; ni < 4; ++ni) {
        int c = ccol + ni * 16;
        float b = 0.f;
        if (g->bias1) b += g->bias1[c];
        if (g->bias2) b += g->bias2[c];
        bv[ni] = b;
    }

    if (g->mode == 1) {
#pragma unroll
        for (int ni = 0; ni < 4; ++ni) {
            int c = ccol + ni * 16;
#pragma unroll
            for (int mi = 0; mi < 4; ++mi) {
#pragma unroll
                for (int j = 0; j < 4; ++j) {
                    int r = crow0 + mi * 16 + j;
                    size_t idx = (size_t)r * H + c;
                    float v = fmaxf(acc[mi][ni][j] + bv[ni], 0.f) + bf2f(g->res[idx]);
                    ((u16*)g->out)[idx] = f2bf(v);
                }
            }
        }
    } else {
        if (tid < 128) rowsq[tid] = 0.f;
        __syncthreads();
#pragma unroll
        for (int mi = 0; mi < 4; ++mi) {
#pragma unroll
            for (int j = 0; j < 4; ++j) {
                float p = 0.f;
#pragma unroll
                for (int ni = 0; ni < 4; ++ni) {
                    float v = acc[mi][ni][j] + bv[ni];
                    p += v * v;
                }
                p += __shfl_xor(p, 1);
                p += __shfl_xor(p, 2);
                p += __shfl_xor(p, 4);
                p += __shfl_xor(p, 8);
                if ((lane & 15) == 0) {
                    int rl = wm * 64 + mi * 16 + ((lane >> 4) << 2) + j;
                    atomicAdd(&rowsq[rl], p);
                }
            }
        }
        __syncthreads();
#pragma unroll
        for (int mi = 0; mi < 4; ++mi) {
#pragma unroll
            for (int j = 0; j < 4; ++j) {
                int rl = wm * 64 + mi * 16 + ((lane >> 4) << 2) + j;
                int r = row0 + rl;
                if (r < g->Mvalid) {
                    float inv = 1.f / fmaxf(sqrtf(rowsq[rl]), 1e-12f);
#pragma unroll
                    for (int ni = 0; ni < 4; ++ni) {
                        int c = ccol + ni * 16;
                        float v = acc[mi][ni][j] + bv[ni];
                        ((float*)g->out)[(size_t)r * H + c] = v * inv;
                    }
                }
            }
        }
    }
}

// ================= projection GEMM: fp32 A (in-kernel cvt), 2-deep pipeline =================
struct ProjArgs2 {
    const float* A[2];
    const u16* Wt[2];
    int K[2];
    int M[2];
    u16* out[2];
    int blkSplit;
};

__global__ __launch_bounds__(512, 4) void gemm_proj_k(ProjArgs2 gg) {
    const int which = blockIdx.x >= gg.blkSplit;
    const int row0 = (blockIdx.x - (which ? gg.blkSplit : 0)) * 128;
    const float* __restrict__ Aptr = gg.A[which];
    const u16* __restrict__ Wt = gg.Wt[which];
    const int K = gg.K[which];
    const int M = gg.M[which];
    u16* __restrict__ outp = gg.out[which];

    __shared__ char lds[3][LDSZ];
    const int tid = threadIdx.x;
    const int lane = tid & 63;
    const int wid = tid >> 6;
    const int wm = wid >> 2;
    const int wn = wid & 3;

    const int srow = tid >> 2;
    const int cunit = tid & 3;
    const int aRow = min(row0 + srow, M - 1);
    const float* pA = Aptr + (size_t)aRow * K + cunit * 8;
    const int aDst = srow * 64 + (cunit ^ ((srow >> 1) & 3)) * 16;

    const int bu1 = cunit ^ ((srow >> 1) & 3);
    const int ofsB1 = srow * K + bu1 * 8;
    const int brow2 = 128 + srow;
    const int bu2 = cunit ^ ((brow2 >> 1) & 3);
    const int ofsB2 = brow2 * K + bu2 * 8;

    int a_off[4], b_off[4];
#pragma unroll
    for (int mi = 0; mi < 4; ++mi) {
        int row = wm * 64 + mi * 16 + (lane & 15);
        int u = (lane >> 4) ^ ((row >> 1) & 3);
        a_off[mi] = row * 64 + u * 16;
    }
#pragma unroll
    for (int ni = 0; ni < 4; ++ni) {
        int row = wn * 64 + ni * 16 + (lane & 15);
        int u = (lane >> 4) ^ ((row >> 1) & 3);
        b_off[ni] = 8192 + row * 64 + u * 16;
    }

#define BSTAGE(kk_, buf_)                                                                         \
    do {                                                                                          \
        __builtin_amdgcn_global_load_lds(                                                         \
            (const __attribute__((address_space(1))) void*)(Wt + ofsB1 + (kk_)),                  \
            (__attribute__((address_space(3))) void*)((buf_) + 8192 + wid * 1024), 16, 0, 0);     \
        __builtin_amdgcn_global_load_lds(                                                         \
            (const __attribute__((address_space(1))) void*)(Wt + ofsB2 + (kk_)),                  \
            (__attribute__((address_space(3))) void*)((buf_) + 16384 + wid * 1024), 16, 0, 0);    \
    } while (0)

    f32x4 acc[4][4] = {};
    const int T = K >> 5;

    char* bufC = lds[0];
    char* bufN = lds[1];
    char* bufS = lds[2];

    // prologue: steps 0 and 1 (B gload_lds + A reg loads, interleaved order preserved)
    BSTAGE(0, bufC);
    float4 cA0 = *reinterpret_cast<const float4*>(pA);
    float4 cA1 = *reinterpret_cast<const float4*>(pA + 4);
    BSTAGE(32, bufN);
    float4 cB0 = *reinterpret_cast<const float4*>(pA + 32);
    float4 cB1 = *reinterpret_cast<const float4*>(pA + 36);

    // body macro: c regs = A(s) slot, refilled with A(s+2)
#define PITER(s_, c0_, c1_)                                                                       \
    do {                                                                                          \
        const int s = (s_);                                                                       \
        if (s + 2 < T) {                                                                          \
            BSTAGE((s + 2) * 32, bufS);                                                           \
            asm volatile("s_waitcnt vmcnt(6)" ::: "memory");                                      \
        } else if (s + 1 < T) {                                                                   \
            asm volatile("s_waitcnt vmcnt(4)" ::: "memory");                                      \
        } else {                                                                                  \
            asm volatile("s_waitcnt vmcnt(0)" ::: "memory");                                      \
        }                                                                                         \
        union { bf16x8 v; u16 e[8]; } pk;                                                         \
        pk.e[0] = f2bf(c0_.x); pk.e[1] = f2bf(c0_.y);                                             \
        pk.e[2] = f2bf(c0_.z); pk.e[3] = f2bf(c0_.w);                                             \
        pk.e[4] = f2bf(c1_.x); pk.e[5] = f2bf(c1_.y);                                             \
        pk.e[6] = f2bf(c1_.z); pk.e[7] = f2bf(c1_.w);                                             \
        *reinterpret_cast<bf16x8*>(bufC + aDst) = pk.v;                                           \
        if (s + 2 < T) {                                                                          \
            c0_ = *reinterpret_cast<const float4*>(pA + (s + 2) * 32);                            \
            c1_ = *reinterpret_cast<const float4*>(pA + (s + 2) * 32 + 4);                        \
        }                                                                                         \
        asm volatile("s_waitcnt lgkmcnt(0)" ::: "memory");                                        \
        __builtin_amdgcn_sched_barrier(0);                                                        \
        __builtin_amdgcn_s_barrier();                                                             \
        bf16x8 af[4], bfr[4];                                                                     \
        _Pragma("unroll")                                                                         \
        for (int mi = 0; mi < 4; ++mi)                                                            \
            af[mi] = *reinterpret_cast<const bf16x8*>(bufC + a_off[mi]);                          \
        _Pragma("unroll")                                                                         \
        for (int ni = 0; ni < 4; ++ni)                                                            \
            bfr[ni] = *reinterpret_cast<const bf16x8*>(bufC + b_off[ni]);                         \
        _Pragma("unroll")                                                                         \
        for (int mi = 0; mi < 4; ++mi)                                                            \
            _Pragma("unroll")                                                                     \
            for (int ni = 0; ni < 4; ++ni)                                                        \
                acc[mi][ni] = __builtin_amdgcn_mfma_f32_16x16x32_bf16(af[mi], bfr[ni],            \
                                                                      acc[mi][ni], 0, 0, 0);      \
        __builtin_amdgcn_sched_barrier(0);                                                        \
        __builtin_amdgcn_s_barrier();                                                             \
        char* t_ = bufC; bufC = bufN; bufN = bufS; bufS = t_;                                     \
    } while (0)

    for (int s2 = 0; s2 < T; s2 += 2) {  // T is even (24 or 32)
        PITER(s2, cA0, cA1);
        PITER(s2 + 1, cB0, cB1);
    }
#undef PITER
#undef BSTAGE

    const int ccol = wn * 64 + (lane & 15);
    const int crow0 = row0 + wm * 64 + ((lane >> 4) << 2);
#pragma unroll
    for (int ni = 0; ni < 4; ++ni) {
        int c = ccol + ni * 16;
#pragma unroll
        for (int mi = 0; mi < 4; ++mi) {
#pragma unroll
            for (int j = 0; j < 4; ++j) {
                int r = crow0 + mi * 16 + j;
                outp[(size_t)r * H + c] = f2bf(acc[mi][ni][j]);
            }
        }
    }
}

extern "C" void kernel_launch(void* const* d_in, const int* in_sizes, int n_in,
                              void* d_out, int out_size, void* d_ws, size_t ws_size,
                              hipStream_t stream) {
    const float* x_e = (const float*)d_in[0];
    const float* x_c = (const float*)d_in[1];
    const int* e_ee = (const int*)d_in[2];
    const int* e_ec = (const int*)d_in[3];
    const int* e_ce = (const int*)d_in[4];
    const float* P_e = (const float*)d_in[5];
    const float* P_c = (const float*)d_in[6];
    const float* Wl1 = (const float*)d_in[7];
    const float* bl1 = (const float*)d_in[8];
    const float* Wr1 = (const float*)d_in[9];
    const float* Wl2 = (const float*)d_in[10];
    const float* bl2 = (const float*)d_in[11];
    const float* Wr2 = (const float*)d_in[12];
    float* out = (float*)d_out;

    const size_t EHp = (size_t)ME_PAD * H;
    const size_t CHp = (size_t)MC_PAD * H;

    u16* us = (u16*)d_ws;
    u16* he0 = us;   us += EHp;
    u16* he1 = us;   us += EHp;
    u16* aggE1 = us; us += EHp;
    u16* aggE2 = us; us += EHp;
    u16* hc0 = us;   us += CHp;
    u16* hc1 = us;   us += CHp;
    u16* aggC = us;  us += CHp;
    u16* PeT = us;   us += H * D_E;
    u16* PcT = us;   us += H * D_C;
    u16* WlT1 = us;  us += 3 * H * H;
    u16* WrT1_1 = us; us += H * H;
    u16* WrT1s = us;  us += H * H;
    u16* WlT2 = us;  us += 3 * H * H;
    u16* WrT2_1 = us; us += H * H;
    u16* WrT2s = us;  us += H * H;

    int* ip = (int*)us;
    int* eePtr = ip;  ip += N_E + 1;
    int* cePtr = ip;  ip += N_E + 1;
    int* ecPtr = ip;  ip += N_C + 1;
    int* curAll = ip; ip += SCAN_N;
    int* srcAll = ip; ip += E_TOT;
    int* cntAll = ip; ip += SCAN_N;
    int* part = ip;   ip += SCAN_N;
    int* bsum = ip;   ip += SCAN_NB + 1;

    const int WHH = H * H;

    // --- CSR build ---
    hipMemsetAsync(cntAll, 0, (size_t)SCAN_N * sizeof(int), stream);
    hist3_k<<<(E_TOT + 255) / 256, 256, 0, stream>>>(e_ee + E_EE, e_ce + E_CE, e_ec + E_EC, cntAll);
    scan_blk_k<<<SCAN_NB, 1024, 0, stream>>>(cntAll, part, bsum);
    scan_top_k<<<1, 1024, 0, stream>>>(bsum);
    scan_out_k<<<SCAN_NB, 1024, 0, stream>>>(part, bsum, eePtr, cePtr, ecPtr, curAll);
    reorder3_k<<<(E_TOT + 255) / 256, 256, 0, stream>>>(e_ee, e_ee + E_EE, e_ce, e_ce + E_CE,
                                                        e_ec, e_ec + E_EC, curAll, srcAll);
    const int* eeSrc = srcAll;
    const int* ceSrc = srcAll + E_EE;
    const int* ecSrc = srcAll + E_EE + E_CE;

    // --- weight prep ---
    {
        TransJobs t{};
        int n = 0;
        auto add = [&](const float* a, const float* b, u16* d, int K) {
            t.a[n] = a; t.b[n] = b; t.dst[n] = d; t.K[n] = K; ++n;
        };
        add(P_e, nullptr, PeT, D_E);
        add(P_c, nullptr, PcT, D_C);
        for (int p = 0; p < 3; ++p) add(Wl1 + p * WHH, nullptr, WlT1 + p * WHH, H);
        for (int p = 0; p < 3; ++p) add(Wl2 + p * WHH, nullptr, WlT2 + p * WHH, H);
        add(Wr1 + 1 * WHH, nullptr, WrT1_1, H);
        add(Wr2 + 1 * WHH, nullptr, WrT2_1, H);
        add(Wr1 + 0 * WHH, Wr1 + 2 * WHH, WrT1s, H);
        add(Wr2 + 0 * WHH, Wr2 + 2 * WHH, WrT2s, H);
        transpose_all_k<<<dim3(D_C / 32, H / 32, 12), dim3(32, 32), 0, stream>>>(t);
    }

    const int gridE = ME_PAD / 128, gridC = MC_PAD / 128;

    // --- projections (merged) ---
    {
        ProjArgs2 g{};
        g.A[0] = x_e; g.Wt[0] = PeT; g.K[0] = D_E; g.M[0] = N_E; g.out[0] = he0;
        g.A[1] = x_c; g.Wt[1] = PcT; g.K[1] = D_C; g.M[1] = N_C; g.out[1] = hc0;
        g.blkSplit = gridE;
        gemm_proj_k<<<gridE + gridC, 512, 0, stream>>>(g);
    }

    const int gBlkE = ME_PAD / 4, gBlkC = MC_PAD / 4;
    const int gTotal = 2 * gBlkE + gBlkC;

    // --- conv1 ---
    {
        GatherArgs a{};
        a.feat[0] = he0; a.rowptr[0] = eePtr; a.srcIdx[0] = eeSrc; a.outAgg[0] = aggE1; a.nDst[0] = N_E;
        a.feat[1] = hc0; a.rowptr[1] = cePtr; a.srcIdx[1] = ceSrc; a.outAgg[1] = aggE2; a.nDst[1] = N_E;
        a.feat[2] = he0; a.rowptr[2] = ecPtr; a.srcIdx[2] = ecSrc; a.outAgg[2] = aggC;  a.nDst[2] = N_C;
        a.blkEnd[0] = gBlkE; a.blkEnd[1] = 2 * gBlkE; a.blkEnd[2] = gTotal;
        gather3_k<<<gTotal, 256, 0, stream>>>(a);
    }
    {
        ConvArgs2 g{};
        g.c[0].A[0] = aggE1; g.c[0].Wt[0] = WlT1 + 0 * WHH;
        g.c[0].A[1] = aggE2; g.c[0].Wt[1] = WlT1 + 2 * WHH;
        g.c[0].A[2] = he0;   g.c[0].Wt[2] = WrT1s;
        g.c[0].nPairs = 3;
        g.c[0].bias1 = bl1 + 0 * H; g.c[0].bias2 = bl1 + 2 * H;
        g.c[0].res = he0; g.c[0].out = he1; g.c[0].mode = 1;
        g.c[1].A[0] = aggC; g.c[1].Wt[0] = WlT1 + 1 * WHH;
        g.c[1].A[1] = hc0;  g.c[1].Wt[1] = WrT1_1;
        g.c[1].nPairs = 2;
        g.c[1].bias1 = bl1 + 1 * H;
        g.c[1].res = hc0; g.c[1].out = hc1; g.c[1].mode = 1;
        g.blkSplit = gridE;
        gemm_conv_k<<<gridE + gridC, 512, 0, stream>>>(g);
    }

    // --- conv2 (fused l2norm, direct to d_out) ---
    {
        GatherArgs a{};
        a.feat[0] = he1; a.rowptr[0] = eePtr; a.srcIdx[0] = eeSrc; a.outAgg[0] = aggE1; a.nDst[0] = N_E;
        a.feat[1] = hc1; a.rowptr[1] = cePtr; a.srcIdx[1] = ceSrc; a.outAgg[1] = aggE2; a.nDst[1] = N_E;
        a.feat[2] = he1; a.rowptr[2] = ecPtr; a.srcIdx[2] = ecSrc; a.outAgg[2] = aggC;  a.nDst[2] = N_C;
        a.blkEnd[0] = gBlkE; a.blkEnd[1] = 2 * gBlkE; a.blkEnd[2] = gTotal;
        gather3_k<<<gTotal, 256, 0, stream>>>(a);
    }
    {
        ConvArgs2 g{};
        g.c[0].A[0] = aggE1; g.c[0].Wt[0] = WlT2 + 0 * WHH;
        g.c[0].A[1] = aggE2; g.c[0].Wt[1] = WlT2 + 2 * WHH;
        g.c[0].A[2] = he1;   g.c[0].Wt[2] = WrT2s;
        g.c[0].nPairs = 3;
        g.c[0].bias1 = bl2 + 0 * H; g.c[0].bias2 = bl2 + 2 * H;
        g.c[0].out = out; g.c[0].Mvalid = N_E; g.c[0].mode = 2;
        g.c[1].A[0] = aggC; g.c[1].Wt[0] = WlT2 + 1 * WHH;
        g.c[1].A[1] = hc1;  g.c[1].Wt[1] = WrT2_1;
        g.c[1].nPairs = 2;
        g.c[1].bias1 = bl2 + 1 * H;
        g.c[1].out = out + (size_t)N_E * H; g.c[1].Mvalid = N_C; g.c[1].mode = 2;
        g.blkSplit = gridE;
        gemm_conv_k<<<gridE + gridC, 512, 0, stream>>>(g);
    }
}